// Round 6
// baseline (798.217 us; speedup 1.0000x reference)
//
#include <hip/hip_runtime.h>
#include <math.h>

#define CC 256       // channels = HEADS * HD
#define HEADS 4
#define HD 64
#define NG 64        // num graphs
#define SCAN_BS 512
#define QKVS 768     // fused QKV output width (Q|K|V), fp16 row stride

typedef __attribute__((ext_vector_type(8))) short s16x8;      // 8 x bf16 (4 VGPRs)
typedef __attribute__((ext_vector_type(4))) float f32x4;
typedef __attribute__((ext_vector_type(4))) _Float16 f16x4;   // 8 B
typedef __attribute__((ext_vector_type(2))) _Float16 f16x2;

static __device__ __forceinline__ float bf2f(unsigned short u) {
  return (float)__builtin_bit_cast(__bf16, u);
}

#if __has_builtin(__builtin_amdgcn_fdot2)
static __device__ __forceinline__ float qkdot(f16x2 q0, f16x2 q1, f16x4 k) {
  f16x2 k0 = {k.x, k.y}, k1 = {k.z, k.w};
  return __builtin_amdgcn_fdot2(q0, k0, __builtin_amdgcn_fdot2(q1, k1, 0.f, false), false);
}
#else
static __device__ __forceinline__ float qkdot(f16x2 q0, f16x2 q1, f16x4 k) {
  return (float)q0.x * (float)k.x + (float)q0.y * (float)k.y +
         (float)q1.x * (float)k.z + (float)q1.y * (float)k.w;
}
#endif

// LDS granule swizzle: 128x32 bf16 tiles, 16B granules, pg = g ^ ((row>>2)&3).
static __device__ __forceinline__ int swz(int row, int g) {
  return row * 32 + (((g) ^ ((row >> 2) & 3)) << 3);
}

// ---------------- fused prologue: hist | wprep | split (independent jobs) ----------
__global__ void prep_kernel(const int* __restrict__ dst, int* __restrict__ deg, int E,
                            const float* __restrict__ Wq, const float* __restrict__ Wk,
                            const float* __restrict__ Wv, const float* __restrict__ bq,
                            const float* __restrict__ bk, const float* __restrict__ bv,
                            unsigned short* __restrict__ Bth, unsigned short* __restrict__ Btl,
                            float* __restrict__ biascat, int L,
                            const float* __restrict__ x, unsigned short* __restrict__ hi,
                            unsigned short* __restrict__ lo, int n4,
                            int nbh, int nbw) {
  int b = blockIdx.x;
  if (b < nbh) {
    int e = b * 256 + threadIdx.x;
    if (e < E) atomicAdd(&deg[dst[e]], 1);
    return;
  }
  b -= nbh;
  if (b < nbw) {
    int idx = b * 256 + threadIdx.x;
    int total = L * QKVS * CC;
    if (idx >= total) return;
    int k = idx & 255;
    int n = (idx >> 8) % QKVS;
    int l = idx / (QKVS * CC);
    int part = n >> 8;
    int nn = n & 255;
    const float* W = part == 0 ? Wq : (part == 1 ? Wk : Wv);
    float v = W[((long)l * CC + k) * CC + nn];
    __bf16 h = (__bf16)v;
    Bth[idx] = __builtin_bit_cast(unsigned short, h);
    Btl[idx] = __builtin_bit_cast(unsigned short, (__bf16)(v - (float)h));
    if (k == 0) {
      const float* bb = part == 0 ? bq : (part == 1 ? bk : bv);
      biascat[l * QKVS + n] = bb[l * CC + nn];
    }
    return;
  }
  b -= nbw;
  int i = b * 256 + threadIdx.x;
  if (i >= n4) return;
  float4 v = ((const float4*)x)[i];
  __bf16 h0 = (__bf16)v.x, h1 = (__bf16)v.y, h2 = (__bf16)v.z, h3 = (__bf16)v.w;
  ushort4 hv = make_ushort4(__builtin_bit_cast(unsigned short, h0),
                            __builtin_bit_cast(unsigned short, h1),
                            __builtin_bit_cast(unsigned short, h2),
                            __builtin_bit_cast(unsigned short, h3));
  ushort4 lv = make_ushort4(__builtin_bit_cast(unsigned short, (__bf16)(v.x - (float)h0)),
                            __builtin_bit_cast(unsigned short, (__bf16)(v.y - (float)h1)),
                            __builtin_bit_cast(unsigned short, (__bf16)(v.z - (float)h2)),
                            __builtin_bit_cast(unsigned short, (__bf16)(v.w - (float)h3)));
  ((ushort4*)hi)[i] = hv;
  ((ushort4*)lo)[i] = lv;
}

// ---------------- CSR scan chain ----------------
__global__ void scan1_kernel(const int* __restrict__ deg, int* __restrict__ exc,
                             int* __restrict__ partial, int n) {
  __shared__ int s[SCAN_BS];
  int t = threadIdx.x;
  int g = blockIdx.x * SCAN_BS + t;
  int v = (g < n) ? deg[g] : 0;
  s[t] = v;
  __syncthreads();
  for (int off = 1; off < SCAN_BS; off <<= 1) {
    int add = (t >= off) ? s[t - off] : 0;
    __syncthreads();
    s[t] += add;
    __syncthreads();
  }
  if (g < n) exc[g] = s[t] - v;
  if (t == SCAN_BS - 1) partial[blockIdx.x] = s[t];
}

__global__ void scan2_kernel(int* __restrict__ partial, int nb) {
  __shared__ int s[SCAN_BS];
  int t = threadIdx.x;
  int v = (t < nb) ? partial[t] : 0;
  s[t] = v;
  __syncthreads();
  for (int off = 1; off < SCAN_BS; off <<= 1) {
    int add = (t >= off) ? s[t - off] : 0;
    __syncthreads();
    s[t] += add;
    __syncthreads();
  }
  if (t < nb) partial[t] = s[t] - v;
}

__global__ void scan3_kernel(const int* __restrict__ exc, const int* __restrict__ partial,
                             int* __restrict__ row_start, int* __restrict__ cursor,
                             int n, int E) {
  int g = blockIdx.x * blockDim.x + threadIdx.x;
  if (g < n) {
    int v = exc[g] + partial[g / SCAN_BS];
    row_start[g] = v;
    cursor[g] = v;
  }
  if (g == n) row_start[n] = E;
}

__global__ void scatter_kernel(const int* __restrict__ srcArr, const int* __restrict__ dstArr,
                               int* __restrict__ cursor, int* __restrict__ csr_src, int E) {
  int e = blockIdx.x * blockDim.x + threadIdx.x;
  if (e < E) {
    int d = dstArr[e];
    int p = atomicAdd(&cursor[d], 1);
    csr_src[p] = srcArr[e];
  }
}

// ---------------- fused QKV GEMM via split-bf16 MFMA ----------------
// XCD-bijective block decode (R4) + swizzled LDS (R5) + ROTATED k-loop (R6):
// next tile's global loads issue BEFORE the current tile's MFMAs, so the
// ~600-900cy HBM latency hides under compute instead of sitting exposed
// between the vmcnt(0)-drain barrier and the LDS write (T3-minimum recipe).
__global__ __launch_bounds__(256) void qkv_gemm(const unsigned short* __restrict__ Ah,
                                                const unsigned short* __restrict__ Al,
                                                const unsigned short* __restrict__ Bh,
                                                const unsigned short* __restrict__ Bl,
                                                const float* __restrict__ biascat,
                                                _Float16* __restrict__ qkvh, int M,
                                                int nmb) {
  // 4 tiles x 128x32 bf16 (swizzled) = 32768 B; epilogue T needs 34816 B.
  __shared__ unsigned short S[17408];
  unsigned short* As_h = S;
  unsigned short* As_l = S + 4096;
  unsigned short* Bs_h = S + 8192;
  unsigned short* Bs_l = S + 12288;
  int t = threadIdx.x;

  // bijective XCD swizzle: blockIdx.x -> lid contiguous per XCD
  int G = 6 * nmb;
  int xcd = blockIdx.x & 7, pos = blockIdx.x >> 3;
  int q8 = G >> 3, r8 = G & 7;
  int lid = (xcd < r8 ? xcd * (q8 + 1) : r8 * (q8 + 1) + (xcd - r8) * q8) + pos;
  int bn = lid % 6, bm = lid / 6;

  int lane = t & 63, wave = t >> 6;
  int mo = (wave >> 1) * 64, no = (wave & 1) * 64;
  int col_l = lane & 15, q = lane >> 4;

  f32x4 acc[4][4];
#pragma unroll
  for (int i = 0; i < 4; ++i)
#pragma unroll
    for (int j = 0; j < 4; ++j) acc[i][j] = (f32x4)0.f;

  int sr = t >> 1;
  int sh = (t & 1) * 16;
  int g0 = (t & 1) * 2;                 // logical granule of sh
  int w0 = swz(sr, g0);                 // swizzled elem offsets for the 2 writes
  int w1 = swz(sr, g0 + 1);
  long arow = (long)bm * 128 + sr;
  bool aval = arow < M;
  const unsigned short* agh = Ah + arow * CC + sh;
  const unsigned short* agl = Al + arow * CC + sh;
  const unsigned short* bgh = Bh + ((long)bn * 128 + sr) * CC + sh;
  const unsigned short* bgl = Bl + ((long)bn * 128 + sr) * CC + sh;
  uint4 zz = make_uint4(0, 0, 0, 0);

  // prologue: load tile kt=0 into registers
  uint4 ah0 = zz, ah1 = zz, al0 = zz, al1 = zz;
  if (aval) {
    ah0 = *(const uint4*)(agh);
    ah1 = *(const uint4*)(agh + 8);
    al0 = *(const uint4*)(agl);
    al1 = *(const uint4*)(agl + 8);
  }
  uint4 bh0 = *(const uint4*)(bgh);
  uint4 bh1 = *(const uint4*)(bgh + 8);
  uint4 bl0 = *(const uint4*)(bgl);
  uint4 bl1 = *(const uint4*)(bgl + 8);

  for (int kt = 0; kt < CC; kt += 32) {
    __syncthreads();                    // all waves done reading LDS (prev kt)
    *(uint4*)&As_h[w0] = ah0;
    *(uint4*)&As_h[w1] = ah1;
    *(uint4*)&As_l[w0] = al0;
    *(uint4*)&As_l[w1] = al1;
    *(uint4*)&Bs_h[w0] = bh0;
    *(uint4*)&Bs_h[w1] = bh1;
    *(uint4*)&Bs_l[w0] = bl0;
    *(uint4*)&Bs_l[w1] = bl1;
    __syncthreads();

    // issue NEXT tile's loads before compute -> latency hides under MFMAs
    int kn = kt + 32;
    if (kn < CC) {
      ah0 = zz; ah1 = zz; al0 = zz; al1 = zz;
      if (aval) {
        ah0 = *(const uint4*)(agh + kn);
        ah1 = *(const uint4*)(agh + kn + 8);
        al0 = *(const uint4*)(agl + kn);
        al1 = *(const uint4*)(agl + kn + 8);
      }
      bh0 = *(const uint4*)(bgh + kn);
      bh1 = *(const uint4*)(bgh + kn + 8);
      bl0 = *(const uint4*)(bgl + kn);
      bl1 = *(const uint4*)(bgl + kn + 8);
    }

    s16x8 afh[4], afl[4], bfh[4], bfl[4];
#pragma unroll
    for (int i = 0; i < 4; ++i) {
      int am = mo + i * 16 + col_l;
      int ao = swz(am, q);
      afh[i] = *(const s16x8*)&As_h[ao];
      afl[i] = *(const s16x8*)&As_l[ao];
      int bnn = no + i * 16 + col_l;
      int bo = swz(bnn, q);
      bfh[i] = *(const s16x8*)&Bs_h[bo];
      bfl[i] = *(const s16x8*)&Bs_l[bo];
    }
#pragma unroll
    for (int i = 0; i < 4; ++i)
#pragma unroll
      for (int j = 0; j < 4; ++j) {
        acc[i][j] = __builtin_amdgcn_mfma_f32_16x16x32_bf16(afh[i], bfh[j], acc[i][j], 0, 0, 0);
        acc[i][j] = __builtin_amdgcn_mfma_f32_16x16x32_bf16(afh[i], bfl[j], acc[i][j], 0, 0, 0);
        acc[i][j] = __builtin_amdgcn_mfma_f32_16x16x32_bf16(afl[i], bfh[j], acc[i][j], 0, 0, 0);
      }
  }

  long rbase = (long)bm * 128 + mo;
  int cbase = bn * 128 + no;
  // unified epilogue: stage fp16 tile in LDS (stride 68), then coalesced rows.
  __syncthreads();                       // other waves may still read fragments
  unsigned short* T = S + wave * 4352;   // 64 x 68 fp16 per wave (wave-private)
#pragma unroll
  for (int j = 0; j < 4; ++j) {
    int col = cbase + j * 16 + col_l;
    float bias = biascat[col];
    int cl = j * 16 + col_l;
#pragma unroll
    for (int i = 0; i < 4; ++i) {
#pragma unroll
      for (int r = 0; r < 4; ++r) {
        int rl = i * 16 + q * 4 + r;
        T[rl * 68 + cl] =
            __builtin_bit_cast(unsigned short, (_Float16)(acc[i][j][r] + bias));
      }
    }
  }
  int ocol = cbase + (lane & 15) * 4;    // 4 fp16 per lane
#pragma unroll
  for (int p = 0; p < 16; ++p) {
    int rl = p * 4 + (lane >> 4);
    uint2 v = *(const uint2*)&T[rl * 68 + (lane & 15) * 4];
    long row = rbase + rl;
    if (row < M) *(uint2*)(qkvh + row * QKVS + ocol) = v;
  }
}

// ---------------- fused attention: wave = node, fp16 QKV gather + fdot2 ----------
// R2 structure (best measured): single 8-edge chunk, two 8B loads per edge,
// compiler-scheduled vmcnt overlap at 40 VGPR. Plateau at ~116 us / 3.84 TB/s
// across three schedules -> random-512B-burst memory-system ceiling.
__global__ __launch_bounds__(256) void attn_fused_kernel(const _Float16* __restrict__ qkv,
                                                         const int* __restrict__ row_start,
                                                         const int* __restrict__ csr_src,
                                                         unsigned short* __restrict__ h_hi,
                                                         unsigned short* __restrict__ h_lo,
                                                         int N, int npx) {
  int b = blockIdx.x;
  int nb = (b & 7) * npx + (b >> 3);
  int wave = threadIdx.x >> 6;
  int lane = threadIdx.x & 63;
  int node = nb * 4 + wave;
  if (node >= N) return;
  int s0 = row_start[node], s1 = row_start[node + 1];

  const f16x4 q4 = *(const f16x4*)(qkv + (size_t)node * QKVS + lane * 4);
  const f16x2 q0 = {q4.x, q4.y};
  const f16x2 q1 = {q4.z, q4.w};

  float m = -1e30f, z = 0.f;
  f32x4 acc = (f32x4)0.f;

  int i = s0;
  for (; i + 8 <= s1; i += 8) {
    int ix[8];
#pragma unroll
    for (int u = 0; u < 8; ++u) ix[u] = csr_src[i + u];
    f16x4 kk[8], vv[8];
#pragma unroll
    for (int u = 0; u < 8; ++u) {
      const _Float16* rowp = qkv + (size_t)ix[u] * QKVS + 256 + lane * 4;
      kk[u] = *(const f16x4*)rowp;          // K
      vv[u] = *(const f16x4*)(rowp + 256);  // V
    }
    float lg[8];
#pragma unroll
    for (int u = 0; u < 8; ++u) {
      float d = qkdot(q0, q1, kk[u]);
#pragma unroll
      for (int off = 1; off < 16; off <<= 1) d += __shfl_xor(d, off, 64);
      lg[u] = d * 0.125f;
    }
    float cm = lg[0];
#pragma unroll
    for (int u = 1; u < 8; ++u) cm = fmaxf(cm, lg[u]);
    float mn = fmaxf(m, cm);
    float sc = __expf(m - mn);
    z *= sc;
    acc *= sc;
    m = mn;
#pragma unroll
    for (int u = 0; u < 8; ++u) {
      float e = __expf(lg[u] - m);
      z += e;
      f32x4 vf = {(float)vv[u].x, (float)vv[u].y, (float)vv[u].z, (float)vv[u].w};
      acc += e * vf;
    }
  }
  for (; i < s1; ++i) {
    int s = csr_src[i];
    const _Float16* rowp = qkv + (size_t)s * QKVS + 256 + lane * 4;
    f16x4 k4 = *(const f16x4*)rowp;
    f16x4 v4 = *(const f16x4*)(rowp + 256);
    float d = qkdot(q0, q1, k4);
#pragma unroll
    for (int off = 1; off < 16; off <<= 1) d += __shfl_xor(d, off, 64);
    float lgs = d * 0.125f;
    float mn = fmaxf(m, lgs);
    float sc = __expf(m - mn);
    float e = __expf(lgs - mn);
    z = z * sc + e;
    f32x4 vf = {(float)v4.x, (float)v4.y, (float)v4.z, (float)v4.w};
    acc = acc * sc + e * vf;
    m = mn;
  }

  float rz = 1.f / (z + 1e-16f);
  float o0 = fmaxf(acc.x * rz, 0.f);
  float o1 = fmaxf(acc.y * rz, 0.f);
  float o2 = fmaxf(acc.z * rz, 0.f);
  float o3 = fmaxf(acc.w * rz, 0.f);
  __bf16 h0 = (__bf16)o0, h1 = (__bf16)o1, h2 = (__bf16)o2, h3 = (__bf16)o3;
  ushort4 ohi = make_ushort4(__builtin_bit_cast(unsigned short, h0),
                             __builtin_bit_cast(unsigned short, h1),
                             __builtin_bit_cast(unsigned short, h2),
                             __builtin_bit_cast(unsigned short, h3));
  ushort4 olo = make_ushort4(__builtin_bit_cast(unsigned short, (__bf16)(o0 - (float)h0)),
                             __builtin_bit_cast(unsigned short, (__bf16)(o1 - (float)h1)),
                             __builtin_bit_cast(unsigned short, (__bf16)(o2 - (float)h2)),
                             __builtin_bit_cast(unsigned short, (__bf16)(o3 - (float)h3)));
  size_t idx = (size_t)node * CC + lane * 4;
  *(ushort4*)(h_hi + idx) = ohi;
  *(ushort4*)(h_lo + idx) = olo;
}

// ---------------- pool: parallel segment-sum with atomics (batch sorted) ----------------
__global__ void pool_kernel(const unsigned short* __restrict__ h_hi,
                            const unsigned short* __restrict__ h_lo,
                            const int* __restrict__ batch,
                            float* __restrict__ gpool, int N) {
  int c = threadIdx.x;
  int n0 = blockIdx.x * 64;
  int n1 = min(n0 + 64, N);
  int cur = batch[n0];
  float acc = 0.f;
  for (int n = n0; n < n1; ++n) {
    int g = batch[n];
    if (g != cur) {
      atomicAdd(&gpool[cur * CC + c], acc);
      acc = 0.f;
      cur = g;
    }
    size_t idx = (size_t)n * CC + c;
    acc += bf2f(h_hi[idx]) + bf2f(h_lo[idx]);
  }
  atomicAdd(&gpool[cur * CC + c], acc);
}

// ---------------- MLP head ----------------
__global__ void head_kernel(const float* __restrict__ gpool, const float* __restrict__ W1,
                            const float* __restrict__ b1, const float* __restrict__ W2,
                            const float* __restrict__ b2, float* __restrict__ out) {
  __shared__ float hid[64];
  int g = blockIdx.x, t = threadIdx.x;
  float acc = b1[t];
  for (int i = 0; i < CC; ++i) acc = fmaf(gpool[g * CC + i], W1[i * 64 + t], acc);
  hid[t] = fmaxf(acc, 0.f);
  __syncthreads();
  if (t < 16) {
    float o = b2[t];
    for (int i = 0; i < 64; ++i) o = fmaf(hid[i], W2[i * 16 + t], o);
    out[g * 16 + t] = o;
  }
}

extern "C" void kernel_launch(void* const* d_in, const int* in_sizes, int n_in,
                              void* d_out, int out_size, void* d_ws, size_t ws_size,
                              hipStream_t stream) {
  const float* x  = (const float*)d_in[0];
  const int* ei   = (const int*)d_in[1];
  const int* batch = (const int*)d_in[2];
  const float* Wq = (const float*)d_in[3];
  const float* bq = (const float*)d_in[4];
  const float* Wk = (const float*)d_in[5];
  const float* bk = (const float*)d_in[6];
  const float* Wv = (const float*)d_in[7];
  const float* bv = (const float*)d_in[8];
  const float* W1 = (const float*)d_in[9];
  const float* b1 = (const float*)d_in[10];
  const float* W2 = (const float*)d_in[11];
  const float* b2 = (const float*)d_in[12];
  float* out = (float*)d_out;

  int N = in_sizes[0] / CC;
  int E = in_sizes[1] / 2;
  int L = in_sizes[3] / (CC * CC);
  const int* src = ei;
  const int* dst = ei + E;

  // workspace budget: keep total < 256 MB
  size_t off = 0;
  auto alloc = [&](size_t bytes) -> void* {
    void* p = (char*)d_ws + off;
    off += (bytes + 255) & ~(size_t)255;
    return p;
  };
  _Float16* qkvh = (_Float16*)alloc((size_t)N * QKVS * 2);            // 76.8 MB
  unsigned short* h_hi = (unsigned short*)alloc((size_t)N * CC * 2);  // 25.6 MB
  unsigned short* h_lo = (unsigned short*)alloc((size_t)N * CC * 2);  // 25.6 MB
  unsigned short* Bth = (unsigned short*)alloc((size_t)L * QKVS * CC * 2);
  unsigned short* Btl = (unsigned short*)alloc((size_t)L * QKVS * CC * 2);
  float* biascat = (float*)alloc((size_t)L * QKVS * 4);
  int* deg = (int*)alloc((size_t)N * 4);
  int* exc = (int*)alloc((size_t)N * 4);
  int* partial = (int*)alloc(SCAN_BS * 4);
  int* row_start = (int*)alloc((size_t)(N + 1) * 4);
  int* cursor = (int*)alloc((size_t)N * 4);
  int* csr_src = (int*)alloc((size_t)E * 4);
  float* gpool = (float*)alloc((size_t)NG * CC * 4);
  // total ~= 137 MB

  // fused prologue: hist | wprep | split (independent; one launch)
  hipMemsetAsync(deg, 0, (size_t)N * 4, stream);
  int eb = (E + 255) / 256;
  int wtot = L * QKVS * CC;
  int nbw = (wtot + 255) / 256;
  int n4 = N * CC / 4;
  int nbs = (n4 + 255) / 256;
  prep_kernel<<<eb + nbw + nbs, 256, 0, stream>>>(dst, deg, E,
                                                  Wq, Wk, Wv, bq, bk, bv,
                                                  Bth, Btl, biascat, L,
                                                  x, h_hi, h_lo, n4, eb, nbw);

  // CSR scan chain
  int nb = (N + SCAN_BS - 1) / SCAN_BS;
  scan1_kernel<<<nb, SCAN_BS, 0, stream>>>(deg, exc, partial, N);
  scan2_kernel<<<1, SCAN_BS, 0, stream>>>(partial, nb);
  scan3_kernel<<<(N + 1 + 255) / 256, 256, 0, stream>>>(exc, partial, row_start, cursor, N, E);
  scatter_kernel<<<eb, 256, 0, stream>>>(src, dst, cursor, csr_src, E);

  // layers
  int nmb = (N + 127) / 128;
  int gemmG = 6 * nmb;                // 1D grid, XCD-swizzled in-kernel
  int nblocks = (N + 3) / 4;          // 4 nodes per block (wave = node)
  int npx = (nblocks + 7) / 8;        // blocks per XCD
  int ngrid = npx * 8;
  for (int l = 0; l < L; ++l) {
    qkv_gemm<<<gemmG, 256, 0, stream>>>(h_hi, h_lo,
                                        Bth + (size_t)l * QKVS * CC,
                                        Btl + (size_t)l * QKVS * CC,
                                        biascat + (size_t)l * QKVS, qkvh, N, nmb);
    attn_fused_kernel<<<ngrid, 256, 0, stream>>>(qkvh, row_start, csr_src,
                                                 h_hi, h_lo, N, npx);
  }

  // pool + head
  hipMemsetAsync(gpool, 0, (size_t)NG * CC * 4, stream);
  pool_kernel<<<(N + 63) / 64, 256, 0, stream>>>(h_hi, h_lo, batch, gpool, N);
  head_kernel<<<NG, 64, 0, stream>>>(gpool, W1, b1, W2, b2, out);
}

// Round 7
// 728.181 us; speedup vs baseline: 1.0962x; 1.0962x over previous
//
#include <hip/hip_runtime.h>
#include <math.h>

#define CC 256       // channels = HEADS * HD
#define HEADS 4
#define HD 64
#define NG 64        // num graphs
#define SCAN_BS 512
#define QKVS 768     // fused QKV output width (Q|K|V), fp16 row stride

typedef __attribute__((ext_vector_type(8))) _Float16 f16x8;   // 8 x fp16 (4 VGPRs)
typedef __attribute__((ext_vector_type(4))) float f32x4;
typedef __attribute__((ext_vector_type(4))) _Float16 f16x4;   // 8 B
typedef __attribute__((ext_vector_type(2))) _Float16 f16x2;

static __device__ __forceinline__ float h2f(unsigned short u) {
  return (float)__builtin_bit_cast(_Float16, u);
}

#if __has_builtin(__builtin_amdgcn_fdot2)
static __device__ __forceinline__ float qkdot(f16x2 q0, f16x2 q1, f16x4 k) {
  f16x2 k0 = {k.x, k.y}, k1 = {k.z, k.w};
  return __builtin_amdgcn_fdot2(q0, k0, __builtin_amdgcn_fdot2(q1, k1, 0.f, false), false);
}
#else
static __device__ __forceinline__ float qkdot(f16x2 q0, f16x2 q1, f16x4 k) {
  return (float)q0.x * (float)k.x + (float)q0.y * (float)k.y +
         (float)q1.x * (float)k.z + (float)q1.y * (float)k.w;
}
#endif

// LDS granule swizzle: 128x32 fp16 tiles, 16B granules, pg = g ^ ((row>>2)&3).
static __device__ __forceinline__ int swz(int row, int g) {
  return row * 32 + (((g) ^ ((row >> 2) & 3)) << 3);
}

// ---------------- fused prologue: hist | wprep | split (independent jobs) ----------
// Weights -> fp16 split pair (Wh + Wl covers ~2^-21 of W; Wl may be subnormal).
// x -> single fp16 h (h's intrinsic error is ~2^-11 from fp16 V anyway).
__global__ void prep_kernel(const int* __restrict__ dst, int* __restrict__ deg, int E,
                            const float* __restrict__ Wq, const float* __restrict__ Wk,
                            const float* __restrict__ Wv, const float* __restrict__ bq,
                            const float* __restrict__ bk, const float* __restrict__ bv,
                            unsigned short* __restrict__ Bth, unsigned short* __restrict__ Btl,
                            float* __restrict__ biascat, int L,
                            const float* __restrict__ x, unsigned short* __restrict__ hq,
                            int n4, int nbh, int nbw) {
  int b = blockIdx.x;
  if (b < nbh) {
    int e = b * 256 + threadIdx.x;
    if (e < E) atomicAdd(&deg[dst[e]], 1);
    return;
  }
  b -= nbh;
  if (b < nbw) {
    int idx = b * 256 + threadIdx.x;
    int total = L * QKVS * CC;
    if (idx >= total) return;
    int k = idx & 255;
    int n = (idx >> 8) % QKVS;
    int l = idx / (QKVS * CC);
    int part = n >> 8;
    int nn = n & 255;
    const float* W = part == 0 ? Wq : (part == 1 ? Wk : Wv);
    float v = W[((long)l * CC + k) * CC + nn];
    _Float16 h = (_Float16)v;
    Bth[idx] = __builtin_bit_cast(unsigned short, h);
    Btl[idx] = __builtin_bit_cast(unsigned short, (_Float16)(v - (float)h));
    if (k == 0) {
      const float* bb = part == 0 ? bq : (part == 1 ? bk : bv);
      biascat[l * QKVS + n] = bb[l * CC + nn];
    }
    return;
  }
  b -= nbw;
  int i = b * 256 + threadIdx.x;
  if (i >= n4) return;
  float4 v = ((const float4*)x)[i];
  ushort4 hv = make_ushort4(__builtin_bit_cast(unsigned short, (_Float16)v.x),
                            __builtin_bit_cast(unsigned short, (_Float16)v.y),
                            __builtin_bit_cast(unsigned short, (_Float16)v.z),
                            __builtin_bit_cast(unsigned short, (_Float16)v.w));
  ((ushort4*)hq)[i] = hv;
}

// ---------------- CSR scan chain ----------------
__global__ void scan1_kernel(const int* __restrict__ deg, int* __restrict__ exc,
                             int* __restrict__ partial, int n) {
  __shared__ int s[SCAN_BS];
  int t = threadIdx.x;
  int g = blockIdx.x * SCAN_BS + t;
  int v = (g < n) ? deg[g] : 0;
  s[t] = v;
  __syncthreads();
  for (int off = 1; off < SCAN_BS; off <<= 1) {
    int add = (t >= off) ? s[t - off] : 0;
    __syncthreads();
    s[t] += add;
    __syncthreads();
  }
  if (g < n) exc[g] = s[t] - v;
  if (t == SCAN_BS - 1) partial[blockIdx.x] = s[t];
}

__global__ void scan2_kernel(int* __restrict__ partial, int nb) {
  __shared__ int s[SCAN_BS];
  int t = threadIdx.x;
  int v = (t < nb) ? partial[t] : 0;
  s[t] = v;
  __syncthreads();
  for (int off = 1; off < SCAN_BS; off <<= 1) {
    int add = (t >= off) ? s[t - off] : 0;
    __syncthreads();
    s[t] += add;
    __syncthreads();
  }
  if (t < nb) partial[t] = s[t] - v;
}

__global__ void scan3_kernel(const int* __restrict__ exc, const int* __restrict__ partial,
                             int* __restrict__ row_start, int* __restrict__ cursor,
                             int n, int E) {
  int g = blockIdx.x * blockDim.x + threadIdx.x;
  if (g < n) {
    int v = exc[g] + partial[g / SCAN_BS];
    row_start[g] = v;
    cursor[g] = v;
  }
  if (g == n) row_start[n] = E;
}

__global__ void scatter_kernel(const int* __restrict__ srcArr, const int* __restrict__ dstArr,
                               int* __restrict__ cursor, int* __restrict__ csr_src, int E) {
  int e = blockIdx.x * blockDim.x + threadIdx.x;
  if (e < E) {
    int d = dstArr[e];
    int p = atomicAdd(&cursor[d], 1);
    csr_src[p] = srcArr[e];
  }
}

// ---------------- fused QKV GEMM: fp16 MFMA, A single + B split ----------------
// XCD-bijective block decode (R4) + swizzled LDS (R5). R7: h is single fp16
// (its error is already ~2^-11 from fp16 V), W stays split -> 2 MFMAs per
// (i,j) instead of 3, A staging/fetch halved. R6's rotated k-loop regressed
// (TLP already covers staging latency) -> R5 loop shape.
__global__ __launch_bounds__(256) void qkv_gemm(const unsigned short* __restrict__ Aq,
                                                const unsigned short* __restrict__ Bh,
                                                const unsigned short* __restrict__ Bl,
                                                const float* __restrict__ biascat,
                                                _Float16* __restrict__ qkvh, int M,
                                                int nmb) {
  // 3 tiles x 128x32 fp16 (swizzled) = 24576 B; epilogue T needs 34816 B.
  __shared__ unsigned short S[17408];
  unsigned short* As   = S;
  unsigned short* Bs_h = S + 4096;
  unsigned short* Bs_l = S + 8192;
  int t = threadIdx.x;

  // bijective XCD swizzle: blockIdx.x -> lid contiguous per XCD
  int G = 6 * nmb;
  int xcd = blockIdx.x & 7, pos = blockIdx.x >> 3;
  int q8 = G >> 3, r8 = G & 7;
  int lid = (xcd < r8 ? xcd * (q8 + 1) : r8 * (q8 + 1) + (xcd - r8) * q8) + pos;
  int bn = lid % 6, bm = lid / 6;

  int lane = t & 63, wave = t >> 6;
  int mo = (wave >> 1) * 64, no = (wave & 1) * 64;
  int col_l = lane & 15, q = lane >> 4;

  f32x4 acc[4][4];
#pragma unroll
  for (int i = 0; i < 4; ++i)
#pragma unroll
    for (int j = 0; j < 4; ++j) acc[i][j] = (f32x4)0.f;

  int sr = t >> 1;
  int sh = (t & 1) * 16;
  int g0 = (t & 1) * 2;                 // logical granule of sh
  int w0 = swz(sr, g0);                 // swizzled elem offsets for the 2 writes
  int w1 = swz(sr, g0 + 1);
  long arow = (long)bm * 128 + sr;
  bool aval = arow < M;
  const unsigned short* ag  = Aq + arow * CC + sh;
  const unsigned short* bgh = Bh + ((long)bn * 128 + sr) * CC + sh;
  const unsigned short* bgl = Bl + ((long)bn * 128 + sr) * CC + sh;
  uint4 zz = make_uint4(0, 0, 0, 0);

  for (int kt = 0; kt < CC; kt += 32) {
    uint4 a0 = zz, a1 = zz;
    if (aval) {
      a0 = *(const uint4*)(ag + kt);
      a1 = *(const uint4*)(ag + kt + 8);
    }
    uint4 bh0 = *(const uint4*)(bgh + kt);
    uint4 bh1 = *(const uint4*)(bgh + kt + 8);
    uint4 bl0 = *(const uint4*)(bgl + kt);
    uint4 bl1 = *(const uint4*)(bgl + kt + 8);
    __syncthreads();
    *(uint4*)&As[w0] = a0;
    *(uint4*)&As[w1] = a1;
    *(uint4*)&Bs_h[w0] = bh0;
    *(uint4*)&Bs_h[w1] = bh1;
    *(uint4*)&Bs_l[w0] = bl0;
    *(uint4*)&Bs_l[w1] = bl1;
    __syncthreads();

    f16x8 af[4], bfh[4], bfl[4];
#pragma unroll
    for (int i = 0; i < 4; ++i) {
      int am = mo + i * 16 + col_l;
      af[i] = *(const f16x8*)&As[swz(am, q)];
      int bnn = no + i * 16 + col_l;
      int bo = swz(bnn, q);
      bfh[i] = *(const f16x8*)&Bs_h[bo];
      bfl[i] = *(const f16x8*)&Bs_l[bo];
    }
#pragma unroll
    for (int i = 0; i < 4; ++i)
#pragma unroll
      for (int j = 0; j < 4; ++j) {
        acc[i][j] = __builtin_amdgcn_mfma_f32_16x16x32_f16(af[i], bfh[j], acc[i][j], 0, 0, 0);
        acc[i][j] = __builtin_amdgcn_mfma_f32_16x16x32_f16(af[i], bfl[j], acc[i][j], 0, 0, 0);
      }
  }

  long rbase = (long)bm * 128 + mo;
  int cbase = bn * 128 + no;
  // unified epilogue: stage fp16 tile in LDS (stride 68), then coalesced rows.
  __syncthreads();                       // other waves may still read fragments
  unsigned short* T = S + wave * 4352;   // 64 x 68 fp16 per wave (wave-private)
#pragma unroll
  for (int j = 0; j < 4; ++j) {
    int col = cbase + j * 16 + col_l;
    float bias = biascat[col];
    int cl = j * 16 + col_l;
#pragma unroll
    for (int i = 0; i < 4; ++i) {
#pragma unroll
      for (int r = 0; r < 4; ++r) {
        int rl = i * 16 + q * 4 + r;
        T[rl * 68 + cl] =
            __builtin_bit_cast(unsigned short, (_Float16)(acc[i][j][r] + bias));
      }
    }
  }
  __syncthreads();
  int ocol = cbase + (lane & 15) * 4;    // 4 fp16 per lane
#pragma unroll
  for (int p = 0; p < 16; ++p) {
    int rl = p * 4 + (lane >> 4);
    uint2 v = *(const uint2*)&T[rl * 68 + (lane & 15) * 4];
    long row = rbase + rl;
    if (row < M) *(uint2*)(qkvh + row * QKVS + ocol) = v;
  }
}

// ---------------- fused attention: wave = node, fp16 QKV gather + fdot2 ----------
// R2 structure (best measured): single 8-edge chunk, two 8B loads per edge,
// compiler-scheduled vmcnt overlap at 40 VGPR. Plateau at ~116 us / 3.84 TB/s
// across three schedules -> random-512B-burst memory-system ceiling.
// R7: h output is single fp16 (write traffic halved).
__global__ __launch_bounds__(256) void attn_fused_kernel(const _Float16* __restrict__ qkv,
                                                         const int* __restrict__ row_start,
                                                         const int* __restrict__ csr_src,
                                                         unsigned short* __restrict__ hq,
                                                         int N, int npx) {
  int b = blockIdx.x;
  int nb = (b & 7) * npx + (b >> 3);
  int wave = threadIdx.x >> 6;
  int lane = threadIdx.x & 63;
  int node = nb * 4 + wave;
  if (node >= N) return;
  int s0 = row_start[node], s1 = row_start[node + 1];

  const f16x4 q4 = *(const f16x4*)(qkv + (size_t)node * QKVS + lane * 4);
  const f16x2 q0 = {q4.x, q4.y};
  const f16x2 q1 = {q4.z, q4.w};

  float m = -1e30f, z = 0.f;
  f32x4 acc = (f32x4)0.f;

  int i = s0;
  for (; i + 8 <= s1; i += 8) {
    int ix[8];
#pragma unroll
    for (int u = 0; u < 8; ++u) ix[u] = csr_src[i + u];
    f16x4 kk[8], vv[8];
#pragma unroll
    for (int u = 0; u < 8; ++u) {
      const _Float16* rowp = qkv + (size_t)ix[u] * QKVS + 256 + lane * 4;
      kk[u] = *(const f16x4*)rowp;          // K
      vv[u] = *(const f16x4*)(rowp + 256);  // V
    }
    float lg[8];
#pragma unroll
    for (int u = 0; u < 8; ++u) {
      float d = qkdot(q0, q1, kk[u]);
#pragma unroll
      for (int off = 1; off < 16; off <<= 1) d += __shfl_xor(d, off, 64);
      lg[u] = d * 0.125f;
    }
    float cm = lg[0];
#pragma unroll
    for (int u = 1; u < 8; ++u) cm = fmaxf(cm, lg[u]);
    float mn = fmaxf(m, cm);
    float sc = __expf(m - mn);
    z *= sc;
    acc *= sc;
    m = mn;
#pragma unroll
    for (int u = 0; u < 8; ++u) {
      float e = __expf(lg[u] - m);
      z += e;
      f32x4 vf = {(float)vv[u].x, (float)vv[u].y, (float)vv[u].z, (float)vv[u].w};
      acc += e * vf;
    }
  }
  for (; i < s1; ++i) {
    int s = csr_src[i];
    const _Float16* rowp = qkv + (size_t)s * QKVS + 256 + lane * 4;
    f16x4 k4 = *(const f16x4*)rowp;
    f16x4 v4 = *(const f16x4*)(rowp + 256);
    float d = qkdot(q0, q1, k4);
#pragma unroll
    for (int off = 1; off < 16; off <<= 1) d += __shfl_xor(d, off, 64);
    float lgs = d * 0.125f;
    float mn = fmaxf(m, lgs);
    float sc = __expf(m - mn);
    float e = __expf(lgs - mn);
    z = z * sc + e;
    f32x4 vf = {(float)v4.x, (float)v4.y, (float)v4.z, (float)v4.w};
    acc = acc * sc + e * vf;
    m = mn;
  }

  float rz = 1.f / (z + 1e-16f);
  float o0 = fmaxf(acc.x * rz, 0.f);
  float o1 = fmaxf(acc.y * rz, 0.f);
  float o2 = fmaxf(acc.z * rz, 0.f);
  float o3 = fmaxf(acc.w * rz, 0.f);
  ushort4 ov = make_ushort4(__builtin_bit_cast(unsigned short, (_Float16)o0),
                            __builtin_bit_cast(unsigned short, (_Float16)o1),
                            __builtin_bit_cast(unsigned short, (_Float16)o2),
                            __builtin_bit_cast(unsigned short, (_Float16)o3));
  size_t idx = (size_t)node * CC + lane * 4;
  *(ushort4*)(hq + idx) = ov;
}

// ---------------- pool: parallel segment-sum with atomics (batch sorted) ----------------
__global__ void pool_kernel(const unsigned short* __restrict__ hq,
                            const int* __restrict__ batch,
                            float* __restrict__ gpool, int N) {
  int c = threadIdx.x;
  int n0 = blockIdx.x * 64;
  int n1 = min(n0 + 64, N);
  int cur = batch[n0];
  float acc = 0.f;
  for (int n = n0; n < n1; ++n) {
    int g = batch[n];
    if (g != cur) {
      atomicAdd(&gpool[cur * CC + c], acc);
      acc = 0.f;
      cur = g;
    }
    acc += h2f(hq[(size_t)n * CC + c]);
  }
  atomicAdd(&gpool[cur * CC + c], acc);
}

// ---------------- MLP head ----------------
__global__ void head_kernel(const float* __restrict__ gpool, const float* __restrict__ W1,
                            const float* __restrict__ b1, const float* __restrict__ W2,
                            const float* __restrict__ b2, float* __restrict__ out) {
  __shared__ float hid[64];
  int g = blockIdx.x, t = threadIdx.x;
  float acc = b1[t];
  for (int i = 0; i < CC; ++i) acc = fmaf(gpool[g * CC + i], W1[i * 64 + t], acc);
  hid[t] = fmaxf(acc, 0.f);
  __syncthreads();
  if (t < 16) {
    float o = b2[t];
    for (int i = 0; i < 64; ++i) o = fmaf(hid[i], W2[i * 16 + t], o);
    out[g * 16 + t] = o;
  }
}

extern "C" void kernel_launch(void* const* d_in, const int* in_sizes, int n_in,
                              void* d_out, int out_size, void* d_ws, size_t ws_size,
                              hipStream_t stream) {
  const float* x  = (const float*)d_in[0];
  const int* ei   = (const int*)d_in[1];
  const int* batch = (const int*)d_in[2];
  const float* Wq = (const float*)d_in[3];
  const float* bq = (const float*)d_in[4];
  const float* Wk = (const float*)d_in[5];
  const float* bk = (const float*)d_in[6];
  const float* Wv = (const float*)d_in[7];
  const float* bv = (const float*)d_in[8];
  const float* W1 = (const float*)d_in[9];
  const float* b1 = (const float*)d_in[10];
  const float* W2 = (const float*)d_in[11];
  const float* b2 = (const float*)d_in[12];
  float* out = (float*)d_out;

  int N = in_sizes[0] / CC;
  int E = in_sizes[1] / 2;
  int L = in_sizes[3] / (CC * CC);
  const int* src = ei;
  const int* dst = ei + E;

  // workspace budget: keep total < 256 MB
  size_t off = 0;
  auto alloc = [&](size_t bytes) -> void* {
    void* p = (char*)d_ws + off;
    off += (bytes + 255) & ~(size_t)255;
    return p;
  };
  _Float16* qkvh = (_Float16*)alloc((size_t)N * QKVS * 2);            // 76.8 MB
  unsigned short* hq = (unsigned short*)alloc((size_t)N * CC * 2);    // 25.6 MB (fp16 h)
  unsigned short* Bth = (unsigned short*)alloc((size_t)L * QKVS * CC * 2);
  unsigned short* Btl = (unsigned short*)alloc((size_t)L * QKVS * CC * 2);
  float* biascat = (float*)alloc((size_t)L * QKVS * 4);
  int* deg = (int*)alloc((size_t)N * 4);
  int* exc = (int*)alloc((size_t)N * 4);
  int* partial = (int*)alloc(SCAN_BS * 4);
  int* row_start = (int*)alloc((size_t)(N + 1) * 4);
  int* cursor = (int*)alloc((size_t)N * 4);
  int* csr_src = (int*)alloc((size_t)E * 4);
  float* gpool = (float*)alloc((size_t)NG * CC * 4);
  // total ~= 112 MB

  // fused prologue: hist | wprep | split (independent; one launch)
  hipMemsetAsync(deg, 0, (size_t)N * 4, stream);
  int eb = (E + 255) / 256;
  int wtot = L * QKVS * CC;
  int nbw = (wtot + 255) / 256;
  int n4 = N * CC / 4;
  int nbs = (n4 + 255) / 256;
  prep_kernel<<<eb + nbw + nbs, 256, 0, stream>>>(dst, deg, E,
                                                  Wq, Wk, Wv, bq, bk, bv,
                                                  Bth, Btl, biascat, L,
                                                  x, hq, n4, eb, nbw);

  // CSR scan chain
  int nb = (N + SCAN_BS - 1) / SCAN_BS;
  scan1_kernel<<<nb, SCAN_BS, 0, stream>>>(deg, exc, partial, N);
  scan2_kernel<<<1, SCAN_BS, 0, stream>>>(partial, nb);
  scan3_kernel<<<(N + 1 + 255) / 256, 256, 0, stream>>>(exc, partial, row_start, cursor, N, E);
  scatter_kernel<<<eb, 256, 0, stream>>>(src, dst, cursor, csr_src, E);

  // layers
  int nmb = (N + 127) / 128;
  int gemmG = 6 * nmb;                // 1D grid, XCD-swizzled in-kernel
  int nblocks = (N + 3) / 4;          // 4 nodes per block (wave = node)
  int npx = (nblocks + 7) / 8;        // blocks per XCD
  int ngrid = npx * 8;
  for (int l = 0; l < L; ++l) {
    qkv_gemm<<<gemmG, 256, 0, stream>>>(hq,
                                        Bth + (size_t)l * QKVS * CC,
                                        Btl + (size_t)l * QKVS * CC,
                                        biascat + (size_t)l * QKVS, qkvh, N, nmb);
    attn_fused_kernel<<<ngrid, 256, 0, stream>>>(qkvh, row_start, csr_src,
                                                 hq, N, npx);
  }

  // pool + head
  hipMemsetAsync(gpool, 0, (size_t)NG * CC * 4, stream);
  pool_kernel<<<(N + 63) / 64, 256, 0, stream>>>(hq, batch, gpool, N);
  head_kernel<<<NG, 64, 0, stream>>>(gpool, W1, b1, W2, b2, out);
}

// Round 8
// 694.903 us; speedup vs baseline: 1.1487x; 1.0479x over previous
//
#include <hip/hip_runtime.h>
#include <math.h>

#define CC 256       // channels = HEADS * HD
#define HEADS 4
#define HD 64
#define NG 64        // num graphs
#define SCAN_BS 512
#define QKVS 768     // fused QKV output width (Q|K|V), fp16 row stride

typedef __attribute__((ext_vector_type(8))) _Float16 f16x8;   // 8 x fp16 (4 VGPRs)
typedef __attribute__((ext_vector_type(4))) float f32x4;
typedef __attribute__((ext_vector_type(4))) _Float16 f16x4;   // 8 B
typedef __attribute__((ext_vector_type(2))) _Float16 f16x2;

static __device__ __forceinline__ float h2f(unsigned short u) {
  return (float)__builtin_bit_cast(_Float16, u);
}

#if __has_builtin(__builtin_amdgcn_fdot2)
static __device__ __forceinline__ float qkdot(f16x2 q0, f16x2 q1, f16x4 k) {
  f16x2 k0 = {k.x, k.y}, k1 = {k.z, k.w};
  return __builtin_amdgcn_fdot2(q0, k0, __builtin_amdgcn_fdot2(q1, k1, 0.f, false), false);
}
#else
static __device__ __forceinline__ float qkdot(f16x2 q0, f16x2 q1, f16x4 k) {
  return (float)q0.x * (float)k.x + (float)q0.y * (float)k.y +
         (float)q1.x * (float)k.z + (float)q1.y * (float)k.w;
}
#endif

// LDS granule swizzle: 128x32 fp16 tiles, 16B granules, pg = g ^ ((row>>2)&3).
static __device__ __forceinline__ int swz(int row, int g) {
  return row * 32 + (((g) ^ ((row >> 2) & 3)) << 3);
}

// ---------------- fused prologue: hist | wprep | split (independent jobs) ----------
// R8: weights single fp16 (output is stored fp16 anyway -> W-lo word was
// precision overkill; single-fp16 W adds ~0.05% rel, same order as storage
// rounding). x -> single fp16 h.
__global__ void prep_kernel(const int* __restrict__ dst, int* __restrict__ deg, int E,
                            const float* __restrict__ Wq, const float* __restrict__ Wk,
                            const float* __restrict__ Wv, const float* __restrict__ bq,
                            const float* __restrict__ bk, const float* __restrict__ bv,
                            unsigned short* __restrict__ Bth,
                            float* __restrict__ biascat, int L,
                            const float* __restrict__ x, unsigned short* __restrict__ hq,
                            int n4, int nbh, int nbw) {
  int b = blockIdx.x;
  if (b < nbh) {
    int e = b * 256 + threadIdx.x;
    if (e < E) atomicAdd(&deg[dst[e]], 1);
    return;
  }
  b -= nbh;
  if (b < nbw) {
    int idx = b * 256 + threadIdx.x;
    int total = L * QKVS * CC;
    if (idx >= total) return;
    int k = idx & 255;
    int n = (idx >> 8) % QKVS;
    int l = idx / (QKVS * CC);
    int part = n >> 8;
    int nn = n & 255;
    const float* W = part == 0 ? Wq : (part == 1 ? Wk : Wv);
    float v = W[((long)l * CC + k) * CC + nn];
    Bth[idx] = __builtin_bit_cast(unsigned short, (_Float16)v);
    if (k == 0) {
      const float* bb = part == 0 ? bq : (part == 1 ? bk : bv);
      biascat[l * QKVS + n] = bb[l * CC + nn];
    }
    return;
  }
  b -= nbw;
  int i = b * 256 + threadIdx.x;
  if (i >= n4) return;
  float4 v = ((const float4*)x)[i];
  ushort4 hv = make_ushort4(__builtin_bit_cast(unsigned short, (_Float16)v.x),
                            __builtin_bit_cast(unsigned short, (_Float16)v.y),
                            __builtin_bit_cast(unsigned short, (_Float16)v.z),
                            __builtin_bit_cast(unsigned short, (_Float16)v.w));
  ((ushort4*)hq)[i] = hv;
}

// ---------------- CSR scan chain ----------------
__global__ void scan1_kernel(const int* __restrict__ deg, int* __restrict__ exc,
                             int* __restrict__ partial, int n) {
  __shared__ int s[SCAN_BS];
  int t = threadIdx.x;
  int g = blockIdx.x * SCAN_BS + t;
  int v = (g < n) ? deg[g] : 0;
  s[t] = v;
  __syncthreads();
  for (int off = 1; off < SCAN_BS; off <<= 1) {
    int add = (t >= off) ? s[t - off] : 0;
    __syncthreads();
    s[t] += add;
    __syncthreads();
  }
  if (g < n) exc[g] = s[t] - v;
  if (t == SCAN_BS - 1) partial[blockIdx.x] = s[t];
}

__global__ void scan2_kernel(int* __restrict__ partial, int nb) {
  __shared__ int s[SCAN_BS];
  int t = threadIdx.x;
  int v = (t < nb) ? partial[t] : 0;
  s[t] = v;
  __syncthreads();
  for (int off = 1; off < SCAN_BS; off <<= 1) {
    int add = (t >= off) ? s[t - off] : 0;
    __syncthreads();
    s[t] += add;
    __syncthreads();
  }
  if (t < nb) partial[t] = s[t] - v;
}

__global__ void scan3_kernel(const int* __restrict__ exc, const int* __restrict__ partial,
                             int* __restrict__ row_start, int* __restrict__ cursor,
                             int n, int E) {
  int g = blockIdx.x * blockDim.x + threadIdx.x;
  if (g < n) {
    int v = exc[g] + partial[g / SCAN_BS];
    row_start[g] = v;
    cursor[g] = v;
  }
  if (g == n) row_start[n] = E;
}

__global__ void scatter_kernel(const int* __restrict__ srcArr, const int* __restrict__ dstArr,
                               int* __restrict__ cursor, int* __restrict__ csr_src, int E) {
  int e = blockIdx.x * blockDim.x + threadIdx.x;
  if (e < E) {
    int d = dstArr[e];
    int p = atomicAdd(&cursor[d], 1);
    csr_src[p] = srcArr[e];
  }
}

// ---------------- fused QKV GEMM: pure fp16 MFMA ----------------
// XCD-bijective block decode (R4) + swizzled LDS (R5) + single-fp16 A and B
// (R7/R8): 16 MFMA + 4 global uint4 + 8 ds_read_b128 per k-step. R6's rotated
// k-loop regressed (TLP covers staging latency) -> simple 2-barrier loop.
__global__ __launch_bounds__(256) void qkv_gemm(const unsigned short* __restrict__ Aq,
                                                const unsigned short* __restrict__ Bh,
                                                const float* __restrict__ biascat,
                                                _Float16* __restrict__ qkvh, int M,
                                                int nmb) {
  // 2 tiles x 128x32 fp16 (swizzled) = 16384 B; epilogue T needs 34816 B.
  __shared__ unsigned short S[17408];
  unsigned short* As = S;
  unsigned short* Bs = S + 4096;
  int t = threadIdx.x;

  // bijective XCD swizzle: blockIdx.x -> lid contiguous per XCD
  int G = 6 * nmb;
  int xcd = blockIdx.x & 7, pos = blockIdx.x >> 3;
  int q8 = G >> 3, r8 = G & 7;
  int lid = (xcd < r8 ? xcd * (q8 + 1) : r8 * (q8 + 1) + (xcd - r8) * q8) + pos;
  int bn = lid % 6, bm = lid / 6;

  int lane = t & 63, wave = t >> 6;
  int mo = (wave >> 1) * 64, no = (wave & 1) * 64;
  int col_l = lane & 15, q = lane >> 4;

  f32x4 acc[4][4];
#pragma unroll
  for (int i = 0; i < 4; ++i)
#pragma unroll
    for (int j = 0; j < 4; ++j) acc[i][j] = (f32x4)0.f;

  int sr = t >> 1;
  int sh = (t & 1) * 16;
  int g0 = (t & 1) * 2;                 // logical granule of sh
  int w0 = swz(sr, g0);                 // swizzled elem offsets for the 2 writes
  int w1 = swz(sr, g0 + 1);
  long arow = (long)bm * 128 + sr;
  bool aval = arow < M;
  const unsigned short* ag = Aq + arow * CC + sh;
  const unsigned short* bg = Bh + ((long)bn * 128 + sr) * CC + sh;
  uint4 zz = make_uint4(0, 0, 0, 0);

  for (int kt = 0; kt < CC; kt += 32) {
    uint4 a0 = zz, a1 = zz;
    if (aval) {
      a0 = *(const uint4*)(ag + kt);
      a1 = *(const uint4*)(ag + kt + 8);
    }
    uint4 b0 = *(const uint4*)(bg + kt);
    uint4 b1 = *(const uint4*)(bg + kt + 8);
    __syncthreads();
    *(uint4*)&As[w0] = a0;
    *(uint4*)&As[w1] = a1;
    *(uint4*)&Bs[w0] = b0;
    *(uint4*)&Bs[w1] = b1;
    __syncthreads();

    f16x8 af[4], bf[4];
#pragma unroll
    for (int i = 0; i < 4; ++i) {
      int am = mo + i * 16 + col_l;
      af[i] = *(const f16x8*)&As[swz(am, q)];
      int bnn = no + i * 16 + col_l;
      bf[i] = *(const f16x8*)&Bs[swz(bnn, q)];
    }
#pragma unroll
    for (int i = 0; i < 4; ++i)
#pragma unroll
      for (int j = 0; j < 4; ++j)
        acc[i][j] = __builtin_amdgcn_mfma_f32_16x16x32_f16(af[i], bf[j], acc[i][j], 0, 0, 0);
  }

  long rbase = (long)bm * 128 + mo;
  int cbase = bn * 128 + no;
  // unified epilogue: stage fp16 tile in LDS (stride 68), then coalesced rows.
  __syncthreads();                       // other waves may still read fragments
  unsigned short* T = S + wave * 4352;   // 64 x 68 fp16 per wave (wave-private)
#pragma unroll
  for (int j = 0; j < 4; ++j) {
    int col = cbase + j * 16 + col_l;
    float bias = biascat[col];
    int cl = j * 16 + col_l;
#pragma unroll
    for (int i = 0; i < 4; ++i) {
#pragma unroll
      for (int r = 0; r < 4; ++r) {
        int rl = i * 16 + q * 4 + r;
        T[rl * 68 + cl] =
            __builtin_bit_cast(unsigned short, (_Float16)(acc[i][j][r] + bias));
      }
    }
  }
  __syncthreads();
  int ocol = cbase + (lane & 15) * 4;    // 4 fp16 per lane
#pragma unroll
  for (int p = 0; p < 16; ++p) {
    int rl = p * 4 + (lane >> 4);
    uint2 v = *(const uint2*)&T[rl * 68 + (lane & 15) * 4];
    long row = rbase + rl;
    if (row < M) *(uint2*)(qkvh + row * QKVS + ocol) = v;
  }
}

// ---------------- fused attention: wave = node, fp16 QKV gather + fdot2 ----------
// R2 structure (best measured): single 8-edge chunk, two 8B loads per edge,
// compiler-scheduled vmcnt overlap. BW-vs-occupancy curve (26%->3.15,
// 52%->3.85, 61%->3.73 TB/s) is flat above ~50% -> random-burst memory
// ceiling; only byte reduction moves it further.
__global__ __launch_bounds__(256) void attn_fused_kernel(const _Float16* __restrict__ qkv,
                                                         const int* __restrict__ row_start,
                                                         const int* __restrict__ csr_src,
                                                         unsigned short* __restrict__ hq,
                                                         int N, int npx) {
  int b = blockIdx.x;
  int nb = (b & 7) * npx + (b >> 3);
  int wave = threadIdx.x >> 6;
  int lane = threadIdx.x & 63;
  int node = nb * 4 + wave;
  if (node >= N) return;
  int s0 = row_start[node], s1 = row_start[node + 1];

  const f16x4 q4 = *(const f16x4*)(qkv + (size_t)node * QKVS + lane * 4);
  const f16x2 q0 = {q4.x, q4.y};
  const f16x2 q1 = {q4.z, q4.w};

  float m = -1e30f, z = 0.f;
  f32x4 acc = (f32x4)0.f;

  int i = s0;
  for (; i + 8 <= s1; i += 8) {
    int ix[8];
#pragma unroll
    for (int u = 0; u < 8; ++u) ix[u] = csr_src[i + u];
    f16x4 kk[8], vv[8];
#pragma unroll
    for (int u = 0; u < 8; ++u) {
      const _Float16* rowp = qkv + (size_t)ix[u] * QKVS + 256 + lane * 4;
      kk[u] = *(const f16x4*)rowp;          // K
      vv[u] = *(const f16x4*)(rowp + 256);  // V
    }
    float lg[8];
#pragma unroll
    for (int u = 0; u < 8; ++u) {
      float d = qkdot(q0, q1, kk[u]);
#pragma unroll
      for (int off = 1; off < 16; off <<= 1) d += __shfl_xor(d, off, 64);
      lg[u] = d * 0.125f;
    }
    float cm = lg[0];
#pragma unroll
    for (int u = 1; u < 8; ++u) cm = fmaxf(cm, lg[u]);
    float mn = fmaxf(m, cm);
    float sc = __expf(m - mn);
    z *= sc;
    acc *= sc;
    m = mn;
#pragma unroll
    for (int u = 0; u < 8; ++u) {
      float e = __expf(lg[u] - m);
      z += e;
      f32x4 vf = {(float)vv[u].x, (float)vv[u].y, (float)vv[u].z, (float)vv[u].w};
      acc += e * vf;
    }
  }
  for (; i < s1; ++i) {
    int s = csr_src[i];
    const _Float16* rowp = qkv + (size_t)s * QKVS + 256 + lane * 4;
    f16x4 k4 = *(const f16x4*)rowp;
    f16x4 v4 = *(const f16x4*)(rowp + 256);
    float d = qkdot(q0, q1, k4);
#pragma unroll
    for (int off = 1; off < 16; off <<= 1) d += __shfl_xor(d, off, 64);
    float lgs = d * 0.125f;
    float mn = fmaxf(m, lgs);
    float sc = __expf(m - mn);
    float e = __expf(lgs - mn);
    z = z * sc + e;
    f32x4 vf = {(float)v4.x, (float)v4.y, (float)v4.z, (float)v4.w};
    acc = acc * sc + e * vf;
    m = mn;
  }

  float rz = 1.f / (z + 1e-16f);
  float o0 = fmaxf(acc.x * rz, 0.f);
  float o1 = fmaxf(acc.y * rz, 0.f);
  float o2 = fmaxf(acc.z * rz, 0.f);
  float o3 = fmaxf(acc.w * rz, 0.f);
  ushort4 ov = make_ushort4(__builtin_bit_cast(unsigned short, (_Float16)o0),
                            __builtin_bit_cast(unsigned short, (_Float16)o1),
                            __builtin_bit_cast(unsigned short, (_Float16)o2),
                            __builtin_bit_cast(unsigned short, (_Float16)o3));
  size_t idx = (size_t)node * CC + lane * 4;
  *(ushort4*)(hq + idx) = ov;
}

// ---------------- pool: parallel segment-sum with atomics (batch sorted) ----------------
__global__ void pool_kernel(const unsigned short* __restrict__ hq,
                            const int* __restrict__ batch,
                            float* __restrict__ gpool, int N) {
  int c = threadIdx.x;
  int n0 = blockIdx.x * 64;
  int n1 = min(n0 + 64, N);
  int cur = batch[n0];
  float acc = 0.f;
  for (int n = n0; n < n1; ++n) {
    int g = batch[n];
    if (g != cur) {
      atomicAdd(&gpool[cur * CC + c], acc);
      acc = 0.f;
      cur = g;
    }
    acc += h2f(hq[(size_t)n * CC + c]);
  }
  atomicAdd(&gpool[cur * CC + c], acc);
}

// ---------------- MLP head ----------------
__global__ void head_kernel(const float* __restrict__ gpool, const float* __restrict__ W1,
                            const float* __restrict__ b1, const float* __restrict__ W2,
                            const float* __restrict__ b2, float* __restrict__ out) {
  __shared__ float hid[64];
  int g = blockIdx.x, t = threadIdx.x;
  float acc = b1[t];
  for (int i = 0; i < CC; ++i) acc = fmaf(gpool[g * CC + i], W1[i * 64 + t], acc);
  hid[t] = fmaxf(acc, 0.f);
  __syncthreads();
  if (t < 16) {
    float o = b2[t];
    for (int i = 0; i < 64; ++i) o = fmaf(hid[i], W2[i * 16 + t], o);
    out[g * 16 + t] = o;
  }
}

extern "C" void kernel_launch(void* const* d_in, const int* in_sizes, int n_in,
                              void* d_out, int out_size, void* d_ws, size_t ws_size,
                              hipStream_t stream) {
  const float* x  = (const float*)d_in[0];
  const int* ei   = (const int*)d_in[1];
  const int* batch = (const int*)d_in[2];
  const float* Wq = (const float*)d_in[3];
  const float* bq = (const float*)d_in[4];
  const float* Wk = (const float*)d_in[5];
  const float* bk = (const float*)d_in[6];
  const float* Wv = (const float*)d_in[7];
  const float* bv = (const float*)d_in[8];
  const float* W1 = (const float*)d_in[9];
  const float* b1 = (const float*)d_in[10];
  const float* W2 = (const float*)d_in[11];
  const float* b2 = (const float*)d_in[12];
  float* out = (float*)d_out;

  int N = in_sizes[0] / CC;
  int E = in_sizes[1] / 2;
  int L = in_sizes[3] / (CC * CC);
  const int* src = ei;
  const int* dst = ei + E;

  // workspace budget: keep total < 256 MB
  size_t off = 0;
  auto alloc = [&](size_t bytes) -> void* {
    void* p = (char*)d_ws + off;
    off += (bytes + 255) & ~(size_t)255;
    return p;
  };
  _Float16* qkvh = (_Float16*)alloc((size_t)N * QKVS * 2);            // 76.8 MB
  unsigned short* hq = (unsigned short*)alloc((size_t)N * CC * 2);    // 25.6 MB (fp16 h)
  unsigned short* Bth = (unsigned short*)alloc((size_t)L * QKVS * CC * 2);
  float* biascat = (float*)alloc((size_t)L * QKVS * 4);
  int* deg = (int*)alloc((size_t)N * 4);
  int* exc = (int*)alloc((size_t)N * 4);
  int* partial = (int*)alloc(SCAN_BS * 4);
  int* row_start = (int*)alloc((size_t)(N + 1) * 4);
  int* cursor = (int*)alloc((size_t)N * 4);
  int* csr_src = (int*)alloc((size_t)E * 4);
  float* gpool = (float*)alloc((size_t)NG * CC * 4);
  // total ~= 110 MB

  // fused prologue: hist | wprep | split (independent; one launch)
  hipMemsetAsync(deg, 0, (size_t)N * 4, stream);
  int eb = (E + 255) / 256;
  int wtot = L * QKVS * CC;
  int nbw = (wtot + 255) / 256;
  int n4 = N * CC / 4;
  int nbs = (n4 + 255) / 256;
  prep_kernel<<<eb + nbw + nbs, 256, 0, stream>>>(dst, deg, E,
                                                  Wq, Wk, Wv, bq, bk, bv,
                                                  Bth, biascat, L,
                                                  x, hq, n4, eb, nbw);

  // CSR scan chain
  int nb = (N + SCAN_BS - 1) / SCAN_BS;
  scan1_kernel<<<nb, SCAN_BS, 0, stream>>>(deg, exc, partial, N);
  scan2_kernel<<<1, SCAN_BS, 0, stream>>>(partial, nb);
  scan3_kernel<<<(N + 1 + 255) / 256, 256, 0, stream>>>(exc, partial, row_start, cursor, N, E);
  scatter_kernel<<<eb, 256, 0, stream>>>(src, dst, cursor, csr_src, E);

  // layers
  int nmb = (N + 127) / 128;
  int gemmG = 6 * nmb;                // 1D grid, XCD-swizzled in-kernel
  int nblocks = (N + 3) / 4;          // 4 nodes per block (wave = node)
  int npx = (nblocks + 7) / 8;        // blocks per XCD
  int ngrid = npx * 8;
  for (int l = 0; l < L; ++l) {
    qkv_gemm<<<gemmG, 256, 0, stream>>>(hq,
                                        Bth + (size_t)l * QKVS * CC,
                                        biascat + (size_t)l * QKVS, qkvh, N, nmb);
    attn_fused_kernel<<<ngrid, 256, 0, stream>>>(qkvh, row_start, csr_src,
                                                 hq, N, npx);
  }

  // pool + head
  hipMemsetAsync(gpool, 0, (size_t)NG * CC * 4, stream);
  pool_kernel<<<(N + 63) / 64, 256, 0, stream>>>(hq, batch, gpool, N);
  head_kernel<<<NG, 64, 0, stream>>>(gpool, W1, b1, W2, b2, out);
}

// Round 9
// 658.036 us; speedup vs baseline: 1.2130x; 1.0560x over previous
//
#include <hip/hip_runtime.h>
#include <math.h>

#define CC 256       // channels = HEADS * HD
#define HEADS 4
#define HD 64
#define NG 64        // num graphs
#define SCAN_BS 512
#define QKVS 768     // fused QKV output width (Q|K|V), fp16 row stride

typedef __attribute__((ext_vector_type(8))) _Float16 f16x8;   // 8 x fp16 (4 VGPRs)
typedef __attribute__((ext_vector_type(4))) float f32x4;
typedef __attribute__((ext_vector_type(4))) _Float16 f16x4;   // 8 B
typedef __attribute__((ext_vector_type(2))) _Float16 f16x2;

static __device__ __forceinline__ float h2f(unsigned short u) {
  return (float)__builtin_bit_cast(_Float16, u);
}

#if __has_builtin(__builtin_amdgcn_fdot2)
static __device__ __forceinline__ float qkdot(f16x2 q0, f16x2 q1, f16x4 k) {
  f16x2 k0 = {k.x, k.y}, k1 = {k.z, k.w};
  return __builtin_amdgcn_fdot2(q0, k0, __builtin_amdgcn_fdot2(q1, k1, 0.f, false), false);
}
#else
static __device__ __forceinline__ float qkdot(f16x2 q0, f16x2 q1, f16x4 k) {
  return (float)q0.x * (float)k.x + (float)q0.y * (float)k.y +
         (float)q1.x * (float)k.z + (float)q1.y * (float)k.w;
}
#endif

// LDS granule swizzle for 128x64 fp16 tiles (128B rows, 8x16B granules/row):
// pg = g ^ (row & 7). Fragment reads (16 consecutive rows, fixed g) spread
// over all 8 granule-groups at 2-way (free); b128 writes land at the 8-way
// b128 floor.
static __device__ __forceinline__ int swz64(int row, int g) {
  return row * 64 + (((g) ^ ((row) & 7)) << 3);
}

// ---------------- fused prologue: hist | wprep | split | gpool-zero ----------
__global__ void prep_kernel(const int* __restrict__ dst, int* __restrict__ deg, int E,
                            const float* __restrict__ Wq, const float* __restrict__ Wk,
                            const float* __restrict__ Wv, const float* __restrict__ bq,
                            const float* __restrict__ bk, const float* __restrict__ bv,
                            unsigned short* __restrict__ Bth,
                            float* __restrict__ biascat, int L,
                            const float* __restrict__ x, unsigned short* __restrict__ hq,
                            float* __restrict__ gpool,
                            int n4, int nbh, int nbw, int nbs) {
  int b = blockIdx.x;
  if (b < nbh) {
    int e = b * 256 + threadIdx.x;
    if (e < E) atomicAdd(&deg[dst[e]], 1);
    return;
  }
  b -= nbh;
  if (b < nbw) {
    int idx = b * 256 + threadIdx.x;
    int total = L * QKVS * CC;
    if (idx >= total) return;
    int k = idx & 255;
    int n = (idx >> 8) % QKVS;
    int l = idx / (QKVS * CC);
    int part = n >> 8;
    int nn = n & 255;
    const float* W = part == 0 ? Wq : (part == 1 ? Wk : Wv);
    float v = W[((long)l * CC + k) * CC + nn];
    Bth[idx] = __builtin_bit_cast(unsigned short, (_Float16)v);
    if (k == 0) {
      const float* bb = part == 0 ? bq : (part == 1 ? bk : bv);
      biascat[l * QKVS + n] = bb[l * CC + nn];
    }
    return;
  }
  b -= nbw;
  if (b < nbs) {
    int i = b * 256 + threadIdx.x;
    if (i >= n4) return;
    float4 v = ((const float4*)x)[i];
    ushort4 hv = make_ushort4(__builtin_bit_cast(unsigned short, (_Float16)v.x),
                              __builtin_bit_cast(unsigned short, (_Float16)v.y),
                              __builtin_bit_cast(unsigned short, (_Float16)v.z),
                              __builtin_bit_cast(unsigned short, (_Float16)v.w));
    ((ushort4*)hq)[i] = hv;
    return;
  }
  b -= nbs;
  int i = b * 256 + threadIdx.x;
  if (i < NG * CC) gpool[i] = 0.f;
}

// ---------------- CSR scan chain ----------------
__global__ void scan1_kernel(const int* __restrict__ deg, int* __restrict__ exc,
                             int* __restrict__ partial, int n) {
  __shared__ int s[SCAN_BS];
  int t = threadIdx.x;
  int g = blockIdx.x * SCAN_BS + t;
  int v = (g < n) ? deg[g] : 0;
  s[t] = v;
  __syncthreads();
  for (int off = 1; off < SCAN_BS; off <<= 1) {
    int add = (t >= off) ? s[t - off] : 0;
    __syncthreads();
    s[t] += add;
    __syncthreads();
  }
  if (g < n) exc[g] = s[t] - v;
  if (t == SCAN_BS - 1) partial[blockIdx.x] = s[t];
}

__global__ void scan2_kernel(int* __restrict__ partial, int nb) {
  __shared__ int s[SCAN_BS];
  int t = threadIdx.x;
  int v = (t < nb) ? partial[t] : 0;
  s[t] = v;
  __syncthreads();
  for (int off = 1; off < SCAN_BS; off <<= 1) {
    int add = (t >= off) ? s[t - off] : 0;
    __syncthreads();
    s[t] += add;
    __syncthreads();
  }
  if (t < nb) partial[t] = s[t] - v;
}

__global__ void scan3_kernel(const int* __restrict__ exc, const int* __restrict__ partial,
                             int* __restrict__ row_start, int* __restrict__ cursor,
                             int n, int E) {
  int g = blockIdx.x * blockDim.x + threadIdx.x;
  if (g < n) {
    int v = exc[g] + partial[g / SCAN_BS];
    row_start[g] = v;
    cursor[g] = v;
  }
  if (g == n) row_start[n] = E;
}

__global__ void scatter_kernel(const int* __restrict__ srcArr, const int* __restrict__ dstArr,
                               int* __restrict__ cursor, int* __restrict__ csr_src, int E) {
  int e = blockIdx.x * blockDim.x + threadIdx.x;
  if (e < E) {
    int d = dstArr[e];
    int p = atomicAdd(&cursor[d], 1);
    csr_src[p] = srcArr[e];
  }
}

// ---------------- fused QKV GEMM: pure fp16 MFMA, BK=64 ----------------
// XCD-bijective block decode (R4) + swizzled LDS (R5, adapted to 128B rows) +
// single-fp16 A/B (R8). R9: BK=64 halves barrier-drain events (16 -> 8) and
// loop iterations at identical bytes/MFMA counts; accumulation order is
// bit-identical to R8.
__global__ __launch_bounds__(256) void qkv_gemm(const unsigned short* __restrict__ Aq,
                                                const unsigned short* __restrict__ Bh,
                                                const float* __restrict__ biascat,
                                                _Float16* __restrict__ qkvh, int M,
                                                int nmb) {
  // 2 tiles x 128x64 fp16 (swizzled) = 32768 B; epilogue T = 4 x 64x72 = 36864 B.
  __shared__ unsigned short S[18432];
  unsigned short* As = S;
  unsigned short* Bs = S + 8192;
  int t = threadIdx.x;

  // bijective XCD swizzle: blockIdx.x -> lid contiguous per XCD
  int G = 6 * nmb;
  int xcd = blockIdx.x & 7, pos = blockIdx.x >> 3;
  int q8 = G >> 3, r8 = G & 7;
  int lid = (xcd < r8 ? xcd * (q8 + 1) : r8 * (q8 + 1) + (xcd - r8) * q8) + pos;
  int bn = lid % 6, bm = lid / 6;

  int lane = t & 63, wave = t >> 6;
  int mo = (wave >> 1) * 64, no = (wave & 1) * 64;
  int col_l = lane & 15, q = lane >> 4;

  f32x4 acc[4][4];
#pragma unroll
  for (int i = 0; i < 4; ++i)
#pragma unroll
    for (int j = 0; j < 4; ++j) acc[i][j] = (f32x4)0.f;

  int sr = t >> 1;            // staged row 0..127
  int h = t & 1;              // column half: cols h*32 .. h*32+31
  long arow = (long)bm * 128 + sr;
  bool aval = arow < M;
  const unsigned short* ag = Aq + arow * CC + h * 32;
  const unsigned short* bg = Bh + ((long)bn * 128 + sr) * CC + h * 32;
  uint4 zz = make_uint4(0, 0, 0, 0);
  int woff[4];
#pragma unroll
  for (int i = 0; i < 4; ++i) woff[i] = swz64(sr, h * 4 + i);

  for (int kt = 0; kt < CC; kt += 64) {
    uint4 a0 = zz, a1 = zz, a2 = zz, a3 = zz;
    if (aval) {
      a0 = *(const uint4*)(ag + kt);
      a1 = *(const uint4*)(ag + kt + 8);
      a2 = *(const uint4*)(ag + kt + 16);
      a3 = *(const uint4*)(ag + kt + 24);
    }
    uint4 b0 = *(const uint4*)(bg + kt);
    uint4 b1 = *(const uint4*)(bg + kt + 8);
    uint4 b2 = *(const uint4*)(bg + kt + 16);
    uint4 b3 = *(const uint4*)(bg + kt + 24);
    __syncthreads();
    *(uint4*)&As[woff[0]] = a0;
    *(uint4*)&As[woff[1]] = a1;
    *(uint4*)&As[woff[2]] = a2;
    *(uint4*)&As[woff[3]] = a3;
    *(uint4*)&Bs[woff[0]] = b0;
    *(uint4*)&Bs[woff[1]] = b1;
    *(uint4*)&Bs[woff[2]] = b2;
    *(uint4*)&Bs[woff[3]] = b3;
    __syncthreads();

#pragma unroll
    for (int kk = 0; kk < 64; kk += 32) {
      int gb = (kk >> 3) + q;         // granule of cols kk + q*8
      f16x8 af[4], bf[4];
#pragma unroll
      for (int i = 0; i < 4; ++i) {
        int am = mo + i * 16 + col_l;
        af[i] = *(const f16x8*)&As[swz64(am, gb)];
        int bnn = no + i * 16 + col_l;
        bf[i] = *(const f16x8*)&Bs[swz64(bnn, gb)];
      }
#pragma unroll
      for (int i = 0; i < 4; ++i)
#pragma unroll
        for (int j = 0; j < 4; ++j)
          acc[i][j] = __builtin_amdgcn_mfma_f32_16x16x32_f16(af[i], bf[j], acc[i][j], 0, 0, 0);
    }
  }

  long rbase = (long)bm * 128 + mo;
  int cbase = bn * 128 + no;
  // epilogue: stage fp16 tile in wave-private LDS (stride 72), 16B coalesced rows.
  __syncthreads();                       // other waves may still read fragments
  unsigned short* T = S + wave * 4608;   // 64 x 72 fp16 per wave (wave-private)
#pragma unroll
  for (int j = 0; j < 4; ++j) {
    int col = cbase + j * 16 + col_l;
    float bias = biascat[col];
    int cl = j * 16 + col_l;
#pragma unroll
    for (int i = 0; i < 4; ++i) {
#pragma unroll
      for (int r = 0; r < 4; ++r) {
        int rl = i * 16 + q * 4 + r;
        T[rl * 72 + cl] =
            __builtin_bit_cast(unsigned short, (_Float16)(acc[i][j][r] + bias));
      }
    }
  }
  int c8 = (lane & 7) * 8;               // 8 fp16 = 16B per lane
  int rq = lane >> 3;                    // 0..7
#pragma unroll
  for (int p = 0; p < 8; ++p) {
    int rl = p * 8 + rq;
    uint4 v = *(const uint4*)&T[rl * 72 + c8];
    long row = rbase + rl;
    if (row < M) *(uint4*)(qkvh + row * QKVS + cbase + c8) = v;
  }
}

// ---------------- fused attention: wave = node, fp16 QKV gather + fdot2 ----------
// R2 structure (best measured). R9: last layer fuses the global-add pool —
// skip the hq write, block-stage the 4 nodes' f32 outputs in LDS, sum across
// waves (batch-uniform fast path), one atomicAdd set per block. N ≡ 0 mod 4,
// so blocks are either fully valid or fully out-of-range: no barrier hazard.
__global__ __launch_bounds__(256) void attn_fused_kernel(const _Float16* __restrict__ qkv,
                                                         const int* __restrict__ row_start,
                                                         const int* __restrict__ csr_src,
                                                         unsigned short* __restrict__ hq,
                                                         const int* __restrict__ batch,
                                                         float* __restrict__ gpool,
                                                         int N, int npx) {
  __shared__ float sh[4][CC];
  __shared__ int shb[4];
  int b = blockIdx.x;
  int nb = (b & 7) * npx + (b >> 3);
  int wave = threadIdx.x >> 6;
  int lane = threadIdx.x & 63;
  int node = nb * 4 + wave;
  if (node >= N) return;
  int s0 = row_start[node], s1 = row_start[node + 1];

  const f16x4 q4 = *(const f16x4*)(qkv + (size_t)node * QKVS + lane * 4);
  const f16x2 q0 = {q4.x, q4.y};
  const f16x2 q1 = {q4.z, q4.w};

  float m = -1e30f, z = 0.f;
  f32x4 acc = (f32x4)0.f;

  int i = s0;
  for (; i + 8 <= s1; i += 8) {
    int ix[8];
#pragma unroll
    for (int u = 0; u < 8; ++u) ix[u] = csr_src[i + u];
    f16x4 kk[8], vv[8];
#pragma unroll
    for (int u = 0; u < 8; ++u) {
      const _Float16* rowp = qkv + (size_t)ix[u] * QKVS + 256 + lane * 4;
      kk[u] = *(const f16x4*)rowp;          // K
      vv[u] = *(const f16x4*)(rowp + 256);  // V
    }
    float lg[8];
#pragma unroll
    for (int u = 0; u < 8; ++u) {
      float d = qkdot(q0, q1, kk[u]);
#pragma unroll
      for (int off = 1; off < 16; off <<= 1) d += __shfl_xor(d, off, 64);
      lg[u] = d * 0.125f;
    }
    float cm = lg[0];
#pragma unroll
    for (int u = 1; u < 8; ++u) cm = fmaxf(cm, lg[u]);
    float mn = fmaxf(m, cm);
    float sc = __expf(m - mn);
    z *= sc;
    acc *= sc;
    m = mn;
#pragma unroll
    for (int u = 0; u < 8; ++u) {
      float e = __expf(lg[u] - m);
      z += e;
      f32x4 vf = {(float)vv[u].x, (float)vv[u].y, (float)vv[u].z, (float)vv[u].w};
      acc += e * vf;
    }
  }
  for (; i < s1; ++i) {
    int s = csr_src[i];
    const _Float16* rowp = qkv + (size_t)s * QKVS + 256 + lane * 4;
    f16x4 k4 = *(const f16x4*)rowp;
    f16x4 v4 = *(const f16x4*)(rowp + 256);
    float d = qkdot(q0, q1, k4);
#pragma unroll
    for (int off = 1; off < 16; off <<= 1) d += __shfl_xor(d, off, 64);
    float lgs = d * 0.125f;
    float mn = fmaxf(m, lgs);
    float sc = __expf(m - mn);
    float e = __expf(lgs - mn);
    z = z * sc + e;
    f32x4 vf = {(float)v4.x, (float)v4.y, (float)v4.z, (float)v4.w};
    acc = acc * sc + e * vf;
    m = mn;
  }

  float rz = 1.f / (z + 1e-16f);
  float o0 = fmaxf(acc.x * rz, 0.f);
  float o1 = fmaxf(acc.y * rz, 0.f);
  float o2 = fmaxf(acc.z * rz, 0.f);
  float o3 = fmaxf(acc.w * rz, 0.f);

  if (gpool == nullptr) {
    ushort4 ov = make_ushort4(__builtin_bit_cast(unsigned short, (_Float16)o0),
                              __builtin_bit_cast(unsigned short, (_Float16)o1),
                              __builtin_bit_cast(unsigned short, (_Float16)o2),
                              __builtin_bit_cast(unsigned short, (_Float16)o3));
    size_t idx = (size_t)node * CC + lane * 4;
    *(ushort4*)(hq + idx) = ov;
  } else {
    // fused global-add pool (last layer): h write skipped entirely
    sh[wave][lane * 4 + 0] = o0;
    sh[wave][lane * 4 + 1] = o1;
    sh[wave][lane * 4 + 2] = o2;
    sh[wave][lane * 4 + 3] = o3;
    if (lane == 0) shb[wave] = batch[node];
    __syncthreads();
    int c = threadIdx.x;                 // channel 0..255
    if (wave == 0 || true) {}            // (all threads participate below)
    int b0 = shb[0], b1 = shb[1], b2 = shb[2], b3 = shb[3];
    if (b0 == b1 && b1 == b2 && b2 == b3) {
      float s = sh[0][c] + sh[1][c] + sh[2][c] + sh[3][c];
      atomicAdd(&gpool[b0 * CC + c], s);
    } else {
      atomicAdd(&gpool[b0 * CC + c], sh[0][c]);
      atomicAdd(&gpool[b1 * CC + c], sh[1][c]);
      atomicAdd(&gpool[b2 * CC + c], sh[2][c]);
      atomicAdd(&gpool[b3 * CC + c], sh[3][c]);
    }
  }
}

// ---------------- MLP head ----------------
__global__ void head_kernel(const float* __restrict__ gpool, const float* __restrict__ W1,
                            const float* __restrict__ b1, const float* __restrict__ W2,
                            const float* __restrict__ b2, float* __restrict__ out) {
  __shared__ float hid[64];
  int g = blockIdx.x, t = threadIdx.x;
  float acc = b1[t];
  for (int i = 0; i < CC; ++i) acc = fmaf(gpool[g * CC + i], W1[i * 64 + t], acc);
  hid[t] = fmaxf(acc, 0.f);
  __syncthreads();
  if (t < 16) {
    float o = b2[t];
    for (int i = 0; i < 64; ++i) o = fmaf(hid[i], W2[i * 16 + t], o);
    out[g * 16 + t] = o;
  }
}

extern "C" void kernel_launch(void* const* d_in, const int* in_sizes, int n_in,
                              void* d_out, int out_size, void* d_ws, size_t ws_size,
                              hipStream_t stream) {
  const float* x  = (const float*)d_in[0];
  const int* ei   = (const int*)d_in[1];
  const int* batch = (const int*)d_in[2];
  const float* Wq = (const float*)d_in[3];
  const float* bq = (const float*)d_in[4];
  const float* Wk = (const float*)d_in[5];
  const float* bk = (const float*)d_in[6];
  const float* Wv = (const float*)d_in[7];
  const float* bv = (const float*)d_in[8];
  const float* W1 = (const float*)d_in[9];
  const float* b1 = (const float*)d_in[10];
  const float* W2 = (const float*)d_in[11];
  const float* b2 = (const float*)d_in[12];
  float* out = (float*)d_out;

  int N = in_sizes[0] / CC;
  int E = in_sizes[1] / 2;
  int L = in_sizes[3] / (CC * CC);
  const int* src = ei;
  const int* dst = ei + E;

  // workspace budget: keep total < 256 MB
  size_t off = 0;
  auto alloc = [&](size_t bytes) -> void* {
    void* p = (char*)d_ws + off;
    off += (bytes + 255) & ~(size_t)255;
    return p;
  };
  _Float16* qkvh = (_Float16*)alloc((size_t)N * QKVS * 2);            // 76.8 MB
  unsigned short* hq = (unsigned short*)alloc((size_t)N * CC * 2);    // 25.6 MB (fp16 h)
  unsigned short* Bth = (unsigned short*)alloc((size_t)L * QKVS * CC * 2);
  float* biascat = (float*)alloc((size_t)L * QKVS * 4);
  int* deg = (int*)alloc((size_t)N * 4);
  int* exc = (int*)alloc((size_t)N * 4);
  int* partial = (int*)alloc(SCAN_BS * 4);
  int* row_start = (int*)alloc((size_t)(N + 1) * 4);
  int* cursor = (int*)alloc((size_t)N * 4);
  int* csr_src = (int*)alloc((size_t)E * 4);
  float* gpool = (float*)alloc((size_t)NG * CC * 4);
  // total ~= 110 MB

  // fused prologue: hist | wprep | split | gpool-zero (independent; one launch)
  hipMemsetAsync(deg, 0, (size_t)N * 4, stream);
  int eb = (E + 255) / 256;
  int wtot = L * QKVS * CC;
  int nbw = (wtot + 255) / 256;
  int n4 = N * CC / 4;
  int nbs = (n4 + 255) / 256;
  int nbz = (NG * CC + 255) / 256;
  prep_kernel<<<eb + nbw + nbs + nbz, 256, 0, stream>>>(dst, deg, E,
                                                        Wq, Wk, Wv, bq, bk, bv,
                                                        Bth, biascat, L,
                                                        x, hq, gpool, n4, eb, nbw, nbs);

  // CSR scan chain
  int nb = (N + SCAN_BS - 1) / SCAN_BS;
  scan1_kernel<<<nb, SCAN_BS, 0, stream>>>(deg, exc, partial, N);
  scan2_kernel<<<1, SCAN_BS, 0, stream>>>(partial, nb);
  scan3_kernel<<<(N + 1 + 255) / 256, 256, 0, stream>>>(exc, partial, row_start, cursor, N, E);
  scatter_kernel<<<eb, 256, 0, stream>>>(src, dst, cursor, csr_src, E);

  // layers
  int nmb = (N + 127) / 128;
  int gemmG = 6 * nmb;                // 1D grid, XCD-swizzled in-kernel
  int nblocks = (N + 3) / 4;          // 4 nodes per block (wave = node)
  int npx = (nblocks + 7) / 8;        // blocks per XCD
  int ngrid = npx * 8;
  for (int l = 0; l < L; ++l) {
    qkv_gemm<<<gemmG, 256, 0, stream>>>(hq,
                                        Bth + (size_t)l * QKVS * CC,
                                        biascat + (size_t)l * QKVS, qkvh, N, nmb);
    attn_fused_kernel<<<ngrid, 256, 0, stream>>>(qkvh, row_start, csr_src, hq,
                                                 batch, (l == L - 1) ? gpool : nullptr,
                                                 N, npx);
  }

  // head
  head_kernel<<<NG, 64, 0, stream>>>(gpool, W1, b1, W2, b2, out);
}

// Round 10
// 657.055 us; speedup vs baseline: 1.2148x; 1.0015x over previous
//
#include <hip/hip_runtime.h>
#include <math.h>

#define CC 256       // channels = HEADS * HD
#define HEADS 4
#define HD 64
#define NG 64        // num graphs
#define SCAN_BS 512
#define QKVS 768     // fused QKV output width (Q|K|V), fp16 row stride

typedef __attribute__((ext_vector_type(8))) _Float16 f16x8;   // 8 x fp16 (4 VGPRs)
typedef __attribute__((ext_vector_type(4))) float f32x4;
typedef __attribute__((ext_vector_type(4))) _Float16 f16x4;   // 8 B
typedef __attribute__((ext_vector_type(2))) _Float16 f16x2;

static __device__ __forceinline__ float h2f(unsigned short u) {
  return (float)__builtin_bit_cast(_Float16, u);
}

#if __has_builtin(__builtin_amdgcn_fdot2)
static __device__ __forceinline__ float qkdot(f16x2 q0, f16x2 q1, f16x4 k) {
  f16x2 k0 = {k.x, k.y}, k1 = {k.z, k.w};
  return __builtin_amdgcn_fdot2(q0, k0, __builtin_amdgcn_fdot2(q1, k1, 0.f, false), false);
}
#else
static __device__ __forceinline__ float qkdot(f16x2 q0, f16x2 q1, f16x4 k) {
  return (float)q0.x * (float)k.x + (float)q0.y * (float)k.y +
         (float)q1.x * (float)k.z + (float)q1.y * (float)k.w;
}
#endif

// LDS granule swizzle for 128x64 fp16 tiles (128B rows, 8x16B granules/row):
// LDS granule (row,pg) holds global granule g = pg ^ (row&7) (XOR involution).
// Reads of logical (row,g) use swz64; writes go through global_load_lds with
// the INVERSE swizzle applied to the per-lane global source address (rule #21:
// linear LDS dest + pre-swizzled source + swizzled read).
static __device__ __forceinline__ int swz64(int row, int g) {
  return row * 64 + (((g) ^ ((row) & 7)) << 3);
}

// direct global->LDS 16B copy (wave-uniform LDS base + lane*16; per-lane gsrc)
static __device__ __forceinline__ void gload16(const unsigned short* g, unsigned short* l) {
  __builtin_amdgcn_global_load_lds((const __attribute__((address_space(1))) void*)g,
                                   (__attribute__((address_space(3))) void*)l, 16, 0, 0);
}

// ---------------- fused prologue: hist | wprep | split | gpool-zero ----------
__global__ void prep_kernel(const int* __restrict__ dst, int* __restrict__ deg, int E,
                            const float* __restrict__ Wq, const float* __restrict__ Wk,
                            const float* __restrict__ Wv, const float* __restrict__ bq,
                            const float* __restrict__ bk, const float* __restrict__ bv,
                            unsigned short* __restrict__ Bth,
                            float* __restrict__ biascat, int L,
                            const float* __restrict__ x, unsigned short* __restrict__ hq,
                            float* __restrict__ gpool,
                            int n4, int nbh, int nbw, int nbs) {
  int b = blockIdx.x;
  if (b < nbh) {
    int e = b * 256 + threadIdx.x;
    if (e < E) atomicAdd(&deg[dst[e]], 1);
    return;
  }
  b -= nbh;
  if (b < nbw) {
    int idx = b * 256 + threadIdx.x;
    int total = L * QKVS * CC;
    if (idx >= total) return;
    int k = idx & 255;
    int n = (idx >> 8) % QKVS;
    int l = idx / (QKVS * CC);
    int part = n >> 8;
    int nn = n & 255;
    const float* W = part == 0 ? Wq : (part == 1 ? Wk : Wv);
    float v = W[((long)l * CC + k) * CC + nn];
    Bth[idx] = __builtin_bit_cast(unsigned short, (_Float16)v);
    if (k == 0) {
      const float* bb = part == 0 ? bq : (part == 1 ? bk : bv);
      biascat[l * QKVS + n] = bb[l * CC + nn];
    }
    return;
  }
  b -= nbw;
  if (b < nbs) {
    int i = b * 256 + threadIdx.x;
    if (i >= n4) return;
    float4 v = ((const float4*)x)[i];
    ushort4 hv = make_ushort4(__builtin_bit_cast(unsigned short, (_Float16)v.x),
                              __builtin_bit_cast(unsigned short, (_Float16)v.y),
                              __builtin_bit_cast(unsigned short, (_Float16)v.z),
                              __builtin_bit_cast(unsigned short, (_Float16)v.w));
    ((ushort4*)hq)[i] = hv;
    return;
  }
  b -= nbs;
  int i = b * 256 + threadIdx.x;
  if (i < NG * CC) gpool[i] = 0.f;
}

// ---------------- CSR scan chain ----------------
__global__ void scan1_kernel(const int* __restrict__ deg, int* __restrict__ exc,
                             int* __restrict__ partial, int n) {
  __shared__ int s[SCAN_BS];
  int t = threadIdx.x;
  int g = blockIdx.x * SCAN_BS + t;
  int v = (g < n) ? deg[g] : 0;
  s[t] = v;
  __syncthreads();
  for (int off = 1; off < SCAN_BS; off <<= 1) {
    int add = (t >= off) ? s[t - off] : 0;
    __syncthreads();
    s[t] += add;
    __syncthreads();
  }
  if (g < n) exc[g] = s[t] - v;
  if (t == SCAN_BS - 1) partial[blockIdx.x] = s[t];
}

__global__ void scan2_kernel(int* __restrict__ partial, int nb) {
  __shared__ int s[SCAN_BS];
  int t = threadIdx.x;
  int v = (t < nb) ? partial[t] : 0;
  s[t] = v;
  __syncthreads();
  for (int off = 1; off < SCAN_BS; off <<= 1) {
    int add = (t >= off) ? s[t - off] : 0;
    __syncthreads();
    s[t] += add;
    __syncthreads();
  }
  if (t < nb) partial[t] = s[t] - v;
}

__global__ void scan3_kernel(const int* __restrict__ exc, const int* __restrict__ partial,
                             int* __restrict__ row_start, int* __restrict__ cursor,
                             int n, int E) {
  int g = blockIdx.x * blockDim.x + threadIdx.x;
  if (g < n) {
    int v = exc[g] + partial[g / SCAN_BS];
    row_start[g] = v;
    cursor[g] = v;
  }
  if (g == n) row_start[n] = E;
}

__global__ void scatter_kernel(const int* __restrict__ srcArr, const int* __restrict__ dstArr,
                               int* __restrict__ cursor, int* __restrict__ csr_src, int E) {
  int e = blockIdx.x * blockDim.x + threadIdx.x;
  if (e < E) {
    int d = dstArr[e];
    int p = atomicAdd(&cursor[d], 1);
    csr_src[p] = srcArr[e];
  }
}

// ---------------- fused QKV GEMM: pure fp16 MFMA, BK=64, global_load_lds ----------------
// XCD-bijective decode (R4) + swizzled LDS (R5) + single-fp16 (R8) + BK=64 (R9).
// R10: staging via global_load_lds width=16 (m151: 874 vs 646 TF vs reg-staging
// at this tile) — no VGPR round-trip, no ds_writes; swizzle folded into the
// per-lane global source address (LDS dest linear per wave, rule #21).
// OOB A-rows of the last bm block read workspace garbage; their C-rows are
// never stored (row < M guard), so zero-fill is unnecessary.
__global__ __launch_bounds__(256) void qkv_gemm(const unsigned short* __restrict__ Aq,
                                                const unsigned short* __restrict__ Bh,
                                                const float* __restrict__ biascat,
                                                _Float16* __restrict__ qkvh, int M,
                                                int nmb) {
  // staging: As 16KB + Bs 16KB; epilogue T = 4 x 64x72 fp16 = 36864 B (reuse).
  __shared__ unsigned short S[18432];
  unsigned short* As = S;
  unsigned short* Bs = S + 8192;
  int t = threadIdx.x;

  // bijective XCD swizzle: blockIdx.x -> lid contiguous per XCD
  int G = 6 * nmb;
  int xcd = blockIdx.x & 7, pos = blockIdx.x >> 3;
  int q8 = G >> 3, r8 = G & 7;
  int lid = (xcd < r8 ? xcd * (q8 + 1) : r8 * (q8 + 1) + (xcd - r8) * q8) + pos;
  int bn = lid % 6, bm = lid / 6;

  int lane = t & 63, wave = t >> 6;
  int mo = (wave >> 1) * 64, no = (wave & 1) * 64;
  int col_l = lane & 15, q = lane >> 4;

  f32x4 acc[4][4];
#pragma unroll
  for (int i = 0; i < 4; ++i)
#pragma unroll
    for (int j = 0; j < 4; ++j) acc[i][j] = (f32x4)0.f;

  // per-round staging geometry: round r covers LDS granules r*256 + wave*64 + lane
  long abase = (long)bm * 128 * CC;
  long bbase = (long)bn * 128 * CC;
  int soff[4];                         // per-lane source elem offset (row*CC + g*8)
  unsigned short* ldsA[4];
  unsigned short* ldsB[4];
#pragma unroll
  for (int r = 0; r < 4; ++r) {
    int gi = r * 256 + wave * 64 + lane;
    int row = gi >> 3;
    int g = (gi & 7) ^ (row & 7);      // inverse-swizzled source granule
    soff[r] = row * CC + g * 8;
    int ub = (r * 256 + wave * 64) * 8;  // wave-uniform LDS elem base
    ldsA[r] = As + ub;
    ldsB[r] = Bs + ub;
  }

  for (int kt = 0; kt < CC; kt += 64) {
    __syncthreads();                   // all waves done reading previous tile
#pragma unroll
    for (int r = 0; r < 4; ++r) {
      gload16(Aq + abase + soff[r] + kt, ldsA[r]);
      gload16(Bh + bbase + soff[r] + kt, ldsB[r]);
    }
    __syncthreads();                   // vmcnt(0) drain: tile resident

#pragma unroll
    for (int kk = 0; kk < 64; kk += 32) {
      int gb = (kk >> 3) + q;          // granule of cols kk + q*8
      f16x8 af[4], bf[4];
#pragma unroll
      for (int i = 0; i < 4; ++i) {
        int am = mo + i * 16 + col_l;
        af[i] = *(const f16x8*)&As[swz64(am, gb)];
        int bnn = no + i * 16 + col_l;
        bf[i] = *(const f16x8*)&Bs[swz64(bnn, gb)];
      }
#pragma unroll
      for (int i = 0; i < 4; ++i)
#pragma unroll
        for (int j = 0; j < 4; ++j)
          acc[i][j] = __builtin_amdgcn_mfma_f32_16x16x32_f16(af[i], bf[j], acc[i][j], 0, 0, 0);
    }
  }

  long rbase = (long)bm * 128 + mo;
  int cbase = bn * 128 + no;
  // epilogue: stage fp16 tile in wave-private LDS (stride 72), 16B coalesced rows.
  __syncthreads();                       // other waves may still read fragments
  unsigned short* T = S + wave * 4608;   // 64 x 72 fp16 per wave (wave-private)
#pragma unroll
  for (int j = 0; j < 4; ++j) {
    int col = cbase + j * 16 + col_l;
    float bias = biascat[col];
    int cl = j * 16 + col_l;
#pragma unroll
    for (int i = 0; i < 4; ++i) {
#pragma unroll
      for (int r = 0; r < 4; ++r) {
        int rl = i * 16 + q * 4 + r;
        T[rl * 72 + cl] =
            __builtin_bit_cast(unsigned short, (_Float16)(acc[i][j][r] + bias));
      }
    }
  }
  int c8 = (lane & 7) * 8;               // 8 fp16 = 16B per lane
  int rq = lane >> 3;                    // 0..7
#pragma unroll
  for (int p = 0; p < 8; ++p) {
    int rl = p * 8 + rq;
    uint4 v = *(const uint4*)&T[rl * 72 + c8];
    long row = rbase + rl;
    if (row < M) *(uint4*)(qkvh + row * QKVS + cbase + c8) = v;
  }
}

// ---------------- fused attention: wave = node, fp16 QKV gather + fdot2 ----------
// R2 structure (best measured). Last layer fuses the global-add pool (R9):
// skip hq write, block-stage the 4 nodes' f32 outputs in LDS, one atomicAdd
// set per block (batch-uniform fast path). N ≡ 0 mod 4 -> blocks fully valid
// or fully out-of-range: no barrier hazard.
__global__ __launch_bounds__(256) void attn_fused_kernel(const _Float16* __restrict__ qkv,
                                                         const int* __restrict__ row_start,
                                                         const int* __restrict__ csr_src,
                                                         unsigned short* __restrict__ hq,
                                                         const int* __restrict__ batch,
                                                         float* __restrict__ gpool,
                                                         int N, int npx) {
  __shared__ float sh[4][CC];
  __shared__ int shb[4];
  int b = blockIdx.x;
  int nb = (b & 7) * npx + (b >> 3);
  int wave = threadIdx.x >> 6;
  int lane = threadIdx.x & 63;
  int node = nb * 4 + wave;
  if (node >= N) return;
  int s0 = row_start[node], s1 = row_start[node + 1];

  const f16x4 q4 = *(const f16x4*)(qkv + (size_t)node * QKVS + lane * 4);
  const f16x2 q0 = {q4.x, q4.y};
  const f16x2 q1 = {q4.z, q4.w};

  float m = -1e30f, z = 0.f;
  f32x4 acc = (f32x4)0.f;

  int i = s0;
  for (; i + 8 <= s1; i += 8) {
    int ix[8];
#pragma unroll
    for (int u = 0; u < 8; ++u) ix[u] = csr_src[i + u];
    f16x4 kk[8], vv[8];
#pragma unroll
    for (int u = 0; u < 8; ++u) {
      const _Float16* rowp = qkv + (size_t)ix[u] * QKVS + 256 + lane * 4;
      kk[u] = *(const f16x4*)rowp;          // K
      vv[u] = *(const f16x4*)(rowp + 256);  // V
    }
    float lg[8];
#pragma unroll
    for (int u = 0; u < 8; ++u) {
      float d = qkdot(q0, q1, kk[u]);
#pragma unroll
      for (int off = 1; off < 16; off <<= 1) d += __shfl_xor(d, off, 64);
      lg[u] = d * 0.125f;
    }
    float cm = lg[0];
#pragma unroll
    for (int u = 1; u < 8; ++u) cm = fmaxf(cm, lg[u]);
    float mn = fmaxf(m, cm);
    float sc = __expf(m - mn);
    z *= sc;
    acc *= sc;
    m = mn;
#pragma unroll
    for (int u = 0; u < 8; ++u) {
      float e = __expf(lg[u] - m);
      z += e;
      f32x4 vf = {(float)vv[u].x, (float)vv[u].y, (float)vv[u].z, (float)vv[u].w};
      acc += e * vf;
    }
  }
  for (; i < s1; ++i) {
    int s = csr_src[i];
    const _Float16* rowp = qkv + (size_t)s * QKVS + 256 + lane * 4;
    f16x4 k4 = *(const f16x4*)rowp;
    f16x4 v4 = *(const f16x4*)(rowp + 256);
    float d = qkdot(q0, q1, k4);
#pragma unroll
    for (int off = 1; off < 16; off <<= 1) d += __shfl_xor(d, off, 64);
    float lgs = d * 0.125f;
    float mn = fmaxf(m, lgs);
    float sc = __expf(m - mn);
    float e = __expf(lgs - mn);
    z = z * sc + e;
    f32x4 vf = {(float)v4.x, (float)v4.y, (float)v4.z, (float)v4.w};
    acc = acc * sc + e * vf;
    m = mn;
  }

  float rz = 1.f / (z + 1e-16f);
  float o0 = fmaxf(acc.x * rz, 0.f);
  float o1 = fmaxf(acc.y * rz, 0.f);
  float o2 = fmaxf(acc.z * rz, 0.f);
  float o3 = fmaxf(acc.w * rz, 0.f);

  if (gpool == nullptr) {
    ushort4 ov = make_ushort4(__builtin_bit_cast(unsigned short, (_Float16)o0),
                              __builtin_bit_cast(unsigned short, (_Float16)o1),
                              __builtin_bit_cast(unsigned short, (_Float16)o2),
                              __builtin_bit_cast(unsigned short, (_Float16)o3));
    size_t idx = (size_t)node * CC + lane * 4;
    *(ushort4*)(hq + idx) = ov;
  } else {
    // fused global-add pool (last layer): h write skipped entirely
    sh[wave][lane * 4 + 0] = o0;
    sh[wave][lane * 4 + 1] = o1;
    sh[wave][lane * 4 + 2] = o2;
    sh[wave][lane * 4 + 3] = o3;
    if (lane == 0) shb[wave] = batch[node];
    __syncthreads();
    int c = threadIdx.x;                 // channel 0..255
    int b0 = shb[0], b1 = shb[1], b2 = shb[2], b3 = shb[3];
    if (b0 == b1 && b1 == b2 && b2 == b3) {
      float s = sh[0][c] + sh[1][c] + sh[2][c] + sh[3][c];
      atomicAdd(&gpool[b0 * CC + c], s);
    } else {
      atomicAdd(&gpool[b0 * CC + c], sh[0][c]);
      atomicAdd(&gpool[b1 * CC + c], sh[1][c]);
      atomicAdd(&gpool[b2 * CC + c], sh[2][c]);
      atomicAdd(&gpool[b3 * CC + c], sh[3][c]);
    }
  }
}

// ---------------- MLP head ----------------
__global__ void head_kernel(const float* __restrict__ gpool, const float* __restrict__ W1,
                            const float* __restrict__ b1, const float* __restrict__ W2,
                            const float* __restrict__ b2, float* __restrict__ out) {
  __shared__ float hid[64];
  int g = blockIdx.x, t = threadIdx.x;
  float acc = b1[t];
  for (int i = 0; i < CC; ++i) acc = fmaf(gpool[g * CC + i], W1[i * 64 + t], acc);
  hid[t] = fmaxf(acc, 0.f);
  __syncthreads();
  if (t < 16) {
    float o = b2[t];
    for (int i = 0; i < 64; ++i) o = fmaf(hid[i], W2[i * 16 + t], o);
    out[g * 16 + t] = o;
  }
}

extern "C" void kernel_launch(void* const* d_in, const int* in_sizes, int n_in,
                              void* d_out, int out_size, void* d_ws, size_t ws_size,
                              hipStream_t stream) {
  const float* x  = (const float*)d_in[0];
  const int* ei   = (const int*)d_in[1];
  const int* batch = (const int*)d_in[2];
  const float* Wq = (const float*)d_in[3];
  const float* bq = (const float*)d_in[4];
  const float* Wk = (const float*)d_in[5];
  const float* bk = (const float*)d_in[6];
  const float* Wv = (const float*)d_in[7];
  const float* bv = (const float*)d_in[8];
  const float* W1 = (const float*)d_in[9];
  const float* b1 = (const float*)d_in[10];
  const float* W2 = (const float*)d_in[11];
  const float* b2 = (const float*)d_in[12];
  float* out = (float*)d_out;

  int N = in_sizes[0] / CC;
  int E = in_sizes[1] / 2;
  int L = in_sizes[3] / (CC * CC);
  const int* src = ei;
  const int* dst = ei + E;

  // workspace budget: keep total < 256 MB
  size_t off = 0;
  auto alloc = [&](size_t bytes) -> void* {
    void* p = (char*)d_ws + off;
    off += (bytes + 255) & ~(size_t)255;
    return p;
  };
  _Float16* qkvh = (_Float16*)alloc((size_t)N * QKVS * 2);            // 76.8 MB
  unsigned short* hq = (unsigned short*)alloc((size_t)N * CC * 2);    // 25.6 MB (fp16 h)
  unsigned short* Bth = (unsigned short*)alloc((size_t)L * QKVS * CC * 2);
  float* biascat = (float*)alloc((size_t)L * QKVS * 4);
  int* deg = (int*)alloc((size_t)N * 4);
  int* exc = (int*)alloc((size_t)N * 4);
  int* partial = (int*)alloc(SCAN_BS * 4);
  int* row_start = (int*)alloc((size_t)(N + 1) * 4);
  int* cursor = (int*)alloc((size_t)N * 4);
  int* csr_src = (int*)alloc((size_t)E * 4);
  float* gpool = (float*)alloc((size_t)NG * CC * 4);
  // total ~= 110 MB

  // fused prologue: hist | wprep | split | gpool-zero (independent; one launch)
  hipMemsetAsync(deg, 0, (size_t)N * 4, stream);
  int eb = (E + 255) / 256;
  int wtot = L * QKVS * CC;
  int nbw = (wtot + 255) / 256;
  int n4 = N * CC / 4;
  int nbs = (n4 + 255) / 256;
  int nbz = (NG * CC + 255) / 256;
  prep_kernel<<<eb + nbw + nbs + nbz, 256, 0, stream>>>(dst, deg, E,
                                                        Wq, Wk, Wv, bq, bk, bv,
                                                        Bth, biascat, L,
                                                        x, hq, gpool, n4, eb, nbw, nbs);

  // CSR scan chain
  int nb = (N + SCAN_BS - 1) / SCAN_BS;
  scan1_kernel<<<nb, SCAN_BS, 0, stream>>>(deg, exc, partial, N);
  scan2_kernel<<<1, SCAN_BS, 0, stream>>>(partial, nb);
  scan3_kernel<<<(N + 1 + 255) / 256, 256, 0, stream>>>(exc, partial, row_start, cursor, N, E);
  scatter_kernel<<<eb, 256, 0, stream>>>(src, dst, cursor, csr_src, E);

  // layers
  int nmb = (N + 127) / 128;
  int gemmG = 6 * nmb;                // 1D grid, XCD-swizzled in-kernel
  int nblocks = (N + 3) / 4;          // 4 nodes per block (wave = node)
  int npx = (nblocks + 7) / 8;        // blocks per XCD
  int ngrid = npx * 8;
  for (int l = 0; l < L; ++l) {
    qkv_gemm<<<gemmG, 256, 0, stream>>>(hq,
                                        Bth + (size_t)l * QKVS * CC,
                                        biascat + (size_t)l * QKVS, qkvh, N, nmb);
    attn_fused_kernel<<<ngrid, 256, 0, stream>>>(qkvh, row_start, csr_src, hq,
                                                 batch, (l == L - 1) ? gpool : nullptr,
                                                 N, npx);
  }

  // head
  head_kernel<<<NG, 64, 0, stream>>>(gpool, W1, b1, W2, b2, out);
}